// Round 7
// baseline (206.939 us; speedup 1.0000x reference)
//
#include <hip/hip_runtime.h>
#include <math.h>

// Problem constants: N=4, L=2048, E=512, H=8, hd=64, FORECAST=8
// M = N*L = 8192 token rows.

#define NEGV -1e30f

typedef __bf16 bf16_t;
typedef __bf16 bf16x4 __attribute__((ext_vector_type(4)));
typedef __bf16 bf16x8 __attribute__((ext_vector_type(8)));
typedef float f32x4 __attribute__((ext_vector_type(4)));

#define MFMA(a, b, c) __builtin_amdgcn_mfma_f32_16x16x32_bf16((a), (b), (c), 0, 0, 0)

// 0.125 * log2(e): folded into Q so scores are already in log2 domain.
#define QSCALE 0.18033688011112042f

// Swizzled LDS access for [*][64]-bf16 tiles (row stride 128 B):
// byte = r*128 + (colbyte ^ ((r&7)<<4)).  Applied on BOTH write and read
// (fattn K/V), or on read-only when the source was PRE-swizzled (GEMMs).
__device__ __forceinline__ bf16x8* swz_ptr(bf16_t* base, int r, int cb) {
  return (bf16x8*)((char*)base + r * 128 + (cb ^ ((r & 7) << 4)));
}
__device__ __forceinline__ const bf16x8* swz_cptr(const bf16_t* base, int r, int cb) {
  return (const bf16x8*)((const char*)base + r * 128 + (cb ^ ((r & 7) << 4)));
}

// async global->LDS, 16 B per lane. LDS dest is wave-uniform base + lane*16;
// global src is per-lane.
__device__ __forceinline__ void gload16(const bf16_t* g, bf16_t* l) {
  __builtin_amdgcn_global_load_lds(
      (const __attribute__((address_space(1))) void*)g,
      (__attribute__((address_space(3))) void*)l, 16, 0, 0);
}

// Pre-swizzle: logical col c (0..63) of a row r stored at:
//   c' = (c & 7) | 8*(((c>>3) ^ (r & 7)) & 7)   [within each 64-col k-block]

// ---------------------------------------------------------------------------
// xconv: Xb[s][k] = bf16(X[s][k]), PRE-SWIZZLED within 64-col k-blocks.
// ---------------------------------------------------------------------------
__global__ __launch_bounds__(256) void xconv(const float* __restrict__ X,
                                             bf16_t* __restrict__ Xb) {
  const int gid = blockIdx.x * 256 + threadIdx.x;
  const int s = gid >> 6, j = gid & 63;  // j: 8-elem block index within row
  const float4* src = (const float4*)(X + (size_t)s * 512 + j * 8);
  const float4 f0 = src[0], f1 = src[1];
  bf16x8 v;
  v[0] = (bf16_t)f0.x; v[1] = (bf16_t)f0.y; v[2] = (bf16_t)f0.z; v[3] = (bf16_t)f0.w;
  v[4] = (bf16_t)f1.x; v[5] = (bf16_t)f1.y; v[6] = (bf16_t)f1.z; v[7] = (bf16_t)f1.w;
  *(bf16x8*)&Xb[(size_t)s * 512 + (j >> 3) * 64 + 8 * ((j & 7) ^ (s & 7))] = v;
}

// ---------------------------------------------------------------------------
// wconv: WT[n][k] = bf16(Wqkv[k][n]), transposed + PRE-SWIZZLED.
// grid (24 n-tiles, 8 k-tiles).
// ---------------------------------------------------------------------------
__global__ __launch_bounds__(256) void wconv(const float* __restrict__ W,
                                             bf16_t* __restrict__ WT) {
  const int n0 = blockIdx.x * 64, k0 = blockIdx.y * 64;
  __shared__ float Wf[64][65];
  const int tid = threadIdx.x;
#pragma unroll
  for (int c = 0; c < 16; ++c) {
    const int idx = tid + c * 256;
    const int kk = idx >> 6, nn = idx & 63;
    Wf[kk][nn] = W[(size_t)(k0 + kk) * 1536 + n0 + nn];
  }
  __syncthreads();
  const int nr = tid >> 2;
  const int jb = (tid & 3) * 2;
#pragma unroll
  for (int t = 0; t < 2; ++t) {
    const int j = jb + t;
    bf16x8 v;
#pragma unroll
    for (int i = 0; i < 8; ++i) v[i] = (bf16_t)Wf[j * 8 + i][nr];
    *(bf16x8*)&WT[(size_t)(n0 + nr) * 512 + k0 + 8 * (j ^ (nr & 7))] = v;
  }
}

// ---------------------------------------------------------------------------
// build_powers: per head h, P = I + (Xi - Xi^T); pows[h][n] = P^(n+1), f32.
// ---------------------------------------------------------------------------
__global__ __launch_bounds__(256) void build_powers(const float* __restrict__ Xi,
                                                    float* __restrict__ pows) {
  const int h = blockIdx.x;
  __shared__ __align__(16) float P[64][68];
  __shared__ __align__(16) float cur[64][68];
  const int tid = threadIdx.x;
  const float* xi = Xi + (size_t)h * 4096;
  float* dst = pows + (size_t)h * 8 * 4096;
  for (int idx = tid; idx < 4096; idx += 256) {
    const int i = idx >> 6, j = idx & 63;
    const float p = (i == j ? 1.f : 0.f) + xi[i * 64 + j] - xi[j * 64 + i];
    P[i][j] = p;
    cur[i][j] = p;
    dst[idx] = p;  // n=0 -> P^1
  }
  __syncthreads();
  const int i = tid >> 2;
  const int j0 = (tid & 3) * 16;
  for (int n = 1; n < 8; ++n) {
    float a[16];
#pragma unroll
    for (int jj = 0; jj < 16; ++jj) a[jj] = 0.f;
    for (int dd = 0; dd < 64; ++dd) {
      const float c = cur[i][dd];
#pragma unroll
      for (int jj = 0; jj < 16; ++jj) a[jj] += c * P[dd][j0 + jj];
    }
    __syncthreads();
#pragma unroll
    for (int jj = 0; jj < 16; ++jj) {
      cur[i][j0 + jj] = a[jj];
      dst[n * 4096 + i * 64 + j0 + jj] = a[jj];
    }
    __syncthreads();
  }
}

// ---------------------------------------------------------------------------
// build_B: BmatT[n][e][(h*64+d)] = sum_dd pows[h][n][d][dd] * Wo[h*64+dd][e]
// Output TRANSPOSED [e][k] and PRE-SWIZZLED within each head's 64-col block.
// grid (4 e-tiles, 8 n, 8 h).
// ---------------------------------------------------------------------------
__global__ __launch_bounds__(256) void build_B(const float* __restrict__ pows,
                                               const float* __restrict__ Wo,
                                               bf16_t* __restrict__ BmatT) {
  const int et = blockIdx.x;
  const int n = blockIdx.y;
  const int h = blockIdx.z;
  __shared__ __align__(16) float P[64][68];
  __shared__ __align__(16) float We[64][128];
  const int tid = threadIdx.x;
  const float* src = pows + ((size_t)h * 8 + n) * 4096;
  for (int idx = tid; idx < 4096; idx += 256) P[idx >> 6][idx & 63] = src[idx];
  const int e0 = et * 128;
  for (int idx = tid; idx < 8192; idx += 256) {
    const int dd = idx >> 7, e = idx & 127;
    We[dd][e] = Wo[(size_t)(h * 64 + dd) * 512 + e0 + e];
  }
  __syncthreads();
  const int d = tid >> 2;
  const int eq = (tid & 3) * 32;  // multiple of 32 -> (e&7) == (j&7)
  float acc[32];
#pragma unroll
  for (int j = 0; j < 32; ++j) acc[j] = 0.f;
  for (int dd = 0; dd < 64; ++dd) {
    const float p = P[d][dd];
#pragma unroll
    for (int j = 0; j < 32; ++j) acc[j] += p * We[dd][eq + j];
  }
  bf16_t* dst = BmatT + (size_t)n * 512 * 512 + (size_t)(e0 + eq) * 512 + h * 64;
  const int dlo = d & 7, dhi = d >> 3;
#pragma unroll
  for (int j = 0; j < 32; ++j)
    dst[(size_t)j * 512 + 8 * (dhi ^ (j & 7)) + dlo] = (bf16_t)acc[j];
}

// ---------------------------------------------------------------------------
// qkv_gemm: qkv = X @ Wqkv + bqkv; A=Xb (pre-swizzled bf16), B=WT (transposed,
// pre-swizzled bf16). global_load_lds staging, linear LDS, swizzled reads.
// ---------------------------------------------------------------------------
__global__ __launch_bounds__(256) void qkv_gemm(const bf16_t* __restrict__ Xb,
                                                const bf16_t* __restrict__ WT,
                                                const float* __restrict__ bias,
                                                bf16_t* __restrict__ qw,
                                                bf16_t* __restrict__ kw,
                                                bf16_t* __restrict__ vt) {
  __shared__ __align__(16) bf16_t As[128 * 64];
  __shared__ __align__(16) bf16_t Bs[128 * 64];
  const int tid = threadIdx.x;
  const int wave = tid >> 6, lane = tid & 63;
  const int g = lane >> 4, li = lane & 15;
  const int row0 = blockIdx.x * 128;
  const int col0 = blockIdx.y * 128;
  const int wm = (wave >> 1) * 64, wn = (wave & 1) * 64;
  f32x4 acc[4][4] = {};
  const bf16_t* asrc = Xb + (size_t)(row0 + wave * 32 + (lane >> 3)) * 512 + (lane & 7) * 8;
  const bf16_t* bsrc = WT + (size_t)(col0 + wave * 32 + (lane >> 3)) * 512 + (lane & 7) * 8;
  bf16_t* adst = &As[wave * 32 * 64];
  bf16_t* bdst = &Bs[wave * 32 * 64];
  for (int k0 = 0; k0 < 512; k0 += 64) {
#pragma unroll
    for (int c = 0; c < 4; ++c) {
      gload16(asrc + (size_t)c * 8 * 512 + k0, adst + c * 512);
      gload16(bsrc + (size_t)c * 8 * 512 + k0, bdst + c * 512);
    }
    __syncthreads();
#pragma unroll
    for (int ks = 0; ks < 2; ++ks) {
      bf16x8 af[4], bfr[4];
#pragma unroll
      for (int mr = 0; mr < 4; ++mr)
        af[mr] = *swz_cptr(As, wm + mr * 16 + li, ks * 64 + g * 16);
#pragma unroll
      for (int nr = 0; nr < 4; ++nr)
        bfr[nr] = *swz_cptr(Bs, wn + nr * 16 + li, ks * 64 + g * 16);
#pragma unroll
      for (int mr = 0; mr < 4; ++mr)
#pragma unroll
        for (int nr = 0; nr < 4; ++nr)
          acc[mr][nr] = MFMA(af[mr], bfr[nr], acc[mr][nr]);
    }
    __syncthreads();
  }
  // epilogue
  const int cbase = col0 + wn;            // multiple of 64
  const int sel = cbase >> 9;             // 0=q 1=k 2=v (uniform per wave)
  const int hh = (cbase & 511) >> 6;      // head (uniform per wave)
  const int bb = row0 >> 11;              // batch (uniform per block)
  const size_t hb = (size_t)(bb * 8 + hh) * (2048 * 64);
  if (sel == 2) {
    // v: transposed store vt[d][s], packed bf16x4 along s
    bf16_t* vbase = vt + hb;
#pragma unroll
    for (int nr = 0; nr < 4; ++nr) {
      const int dcol = nr * 16 + li;
      const float bv = bias[cbase + dcol];
#pragma unroll
      for (int mr = 0; mr < 4; ++mr) {
        bf16x4 pk;
#pragma unroll
        for (int i = 0; i < 4; ++i) pk[i] = (bf16_t)(acc[mr][nr][i] + bv);
        const int s = (row0 + wm + mr * 16 + g * 4) & 2047;
        *(bf16x4*)&vbase[(size_t)dcol * 2048 + s] = pk;
      }
    }
  } else {
    bf16_t* dstp = (sel == 0 ? qw : kw) + hb;
    const float sc = (sel == 0) ? QSCALE : 1.0f;
#pragma unroll
    for (int nr = 0; nr < 4; ++nr) {
      const int dcol = nr * 16 + li;
      const float bv = bias[cbase + dcol];
#pragma unroll
      for (int mr = 0; mr < 4; ++mr) {
#pragma unroll
        for (int i = 0; i < 4; ++i) {
          const int r = row0 + wm + mr * 16 + g * 4 + i;
          const int s = r & 2047;
          dstp[(size_t)s * 64 + dcol] = (bf16_t)((acc[mr][nr][i] + bv) * sc);
        }
      }
    }
  }
}

// ---------------------------------------------------------------------------
// fattn v7: QBLK=128. grid (16 q-tiles reversed, 8 h, 4 b), 4 waves; wave w
// owns rows q0 + w*32 + {0..31} as two 16-row groups (u=0,1).
// K-fragments ds_read ONCE per K-tile, used by both groups; V per group.
// K/V double-buffered swizzled LDS; one barrier per tile; T14 async staging;
// T13 defer-max; T5 setprio. Fully-masked groups skip compute.
// Epilogue stores attn PRE-SWIZZLED for out_gemm's gload_lds.
// ---------------------------------------------------------------------------
__global__ __launch_bounds__(256) void fattn(const bf16_t* __restrict__ qw,
                                             const bf16_t* __restrict__ kw,
                                             const bf16_t* __restrict__ vt,
                                             bf16_t* __restrict__ attn) {
  __shared__ __align__(16) bf16_t Ks[2][64][64];
  __shared__ __align__(16) bf16_t Vs[2][64][64];  // rows = d, cols = key
  __shared__ __align__(16) bf16_t Ps[4][16][64];  // wave-private, swizzled, reused per u
  const int tid = threadIdx.x;
  const int w = tid >> 6;
  const int lane = tid & 63;
  const int g = lane >> 4;
  const int li = lane & 15;
  const int qt = 15 - (int)blockIdx.x;  // longest blocks first
  const int h = blockIdx.y;
  const int b = blockIdx.z;
  const size_t base = ((size_t)(b * 8 + h)) * (2048 * 64);
  const int q0 = qt * 128;
  const int rbase0 = q0 + w * 32;  // group u rows: rbase0 + u*16 + li
  bf16x8 aq[2][2];
#pragma unroll
  for (int u = 0; u < 2; ++u) {
    const bf16_t* qp = qw + base + (size_t)(rbase0 + u * 16 + li) * 64 + g * 8;
    aq[u][0] = *(const bf16x8*)qp;
    aq[u][1] = *(const bf16x8*)(qp + 32);
  }
  const bf16_t* kbase = kw + base;
  const bf16_t* vbase = vt + base;  // [64][2048]
  const int r_st = tid >> 2;  // staging row 0..63
  const int qu = tid & 3;     // staging quarter
  // prologue: stage tile 0 into buffer 0 (swizzled)
  {
    const bf16_t* kp = kbase + (size_t)r_st * 64 + qu * 16;
    const bf16_t* vp = vbase + (size_t)r_st * 2048 + qu * 16;
    *swz_ptr(&Ks[0][0][0], r_st, qu * 32) = *(const bf16x8*)kp;
    *swz_ptr(&Ks[0][0][0], r_st, qu * 32 + 16) = *(const bf16x8*)(kp + 8);
    *swz_ptr(&Vs[0][0][0], r_st, qu * 32) = *(const bf16x8*)vp;
    *swz_ptr(&Vs[0][0][0], r_st, qu * 32 + 16) = *(const bf16x8*)(vp + 8);
  }
  f32x4 accO[2][4] = {};  // [u][nt]: q=li, d = nt*16 + g*4 + i
  float m_run[2] = {-__builtin_inff(), -__builtin_inff()};
  float l_run[2] = {0.f, 0.f};
  char* const psrow = (char*)&Ps[w][li][0];
  const int pswz = (li & 7) << 4;
  const int lim = 2 * qt + 2;
  for (int kt = 0; kt < lim; ++kt) {
    __syncthreads();  // buf[cur] fully staged; previous compute done
    const int cur = kt & 1;
    const bool pf = (kt + 1) < lim;
    const int kb = kt * 64;
    // T14: issue next tile's global loads now; they land during the MFMA phase
    bf16x8 nk0, nk1, nv0, nv1;
    if (pf) {
      const int kb2 = kb + 64;
      const bf16_t* kp = kbase + (size_t)(kb2 + r_st) * 64 + qu * 16;
      const bf16_t* vp = vbase + (size_t)r_st * 2048 + kb2 + qu * 16;
      nk0 = *(const bf16x8*)kp;
      nk1 = *(const bf16x8*)(kp + 8);
      nv0 = *(const bf16x8*)vp;
      nv1 = *(const bf16x8*)(vp + 8);
    }
    // K fragments once (shared by both q-groups)
    bf16x8 bk[8];
#pragma unroll
    for (int nt = 0; nt < 4; ++nt) {
      bk[2 * nt] = *swz_cptr(&Ks[cur][0][0], nt * 16 + li, g * 16);
      bk[2 * nt + 1] = *swz_cptr(&Ks[cur][0][0], nt * 16 + li, 64 + g * 16);
    }
#pragma unroll
    for (int u = 0; u < 2; ++u) {
      const int rbase = rbase0 + u * 16;
      if (kb > rbase + 15) continue;  // fully masked for this group
      f32x4 sv[4];
      __builtin_amdgcn_s_setprio(1);
#pragma unroll
      for (int nt = 0; nt < 4; ++nt) {
        f32x4 z = {0.f, 0.f, 0.f, 0.f};
        z = MFMA(bk[2 * nt], aq[u][0], z);
        sv[nt] = MFMA(bk[2 * nt + 1], aq[u][1], z);
      }
      __builtin_amdgcn_s_setprio(0);
      if (kb + 63 > rbase) {  // diagonal band: elementwise causal mask
#pragma unroll
        for (int nt = 0; nt < 4; ++nt)
#pragma unroll
          for (int i = 0; i < 4; ++i)
            if (kb + nt * 16 + g * 4 + i > rbase + li) sv[nt][i] = NEGV;
      }
      // row max: 15 in-lane + 2 shuffles
      float pmax = sv[0][0];
#pragma unroll
      for (int nt = 0; nt < 4; ++nt)
#pragma unroll
        for (int i = 0; i < 4; ++i) pmax = fmaxf(pmax, sv[nt][i]);
      pmax = fmaxf(pmax, __shfl_xor(pmax, 16, 64));
      pmax = fmaxf(pmax, __shfl_xor(pmax, 32, 64));
      // T13 defer-max
      if (!__all(pmax - m_run[u] <= 8.f)) {
        const float newm = fmaxf(m_run[u], pmax);
        const float sc = exp2f(m_run[u] - newm);
        l_run[u] *= sc;
        m_run[u] = newm;
#pragma unroll
        for (int nt = 0; nt < 4; ++nt)
#pragma unroll
          for (int i = 0; i < 4; ++i) accO[u][nt][i] *= sc;
      }
      float rsum = 0.f;
#pragma unroll
      for (int nt = 0; nt < 4; ++nt) {
#pragma unroll
        for (int i = 0; i < 4; ++i) {
          const float p = exp2f(sv[nt][i] - m_run[u]);
          sv[nt][i] = p;
          rsum += p;
        }
      }
      rsum += __shfl_xor(rsum, 16, 64);
      rsum += __shfl_xor(rsum, 32, 64);
      l_run[u] += rsum;
      // P -> wave-private LDS (swizzled); in-order DS pipe makes reuse safe
#pragma unroll
      for (int nt = 0; nt < 4; ++nt) {
        bf16x4 pk;
#pragma unroll
        for (int i = 0; i < 4; ++i) pk[i] = (bf16_t)sv[nt][i];
        *(bf16x4*)(psrow + ((nt * 32 + g * 8) ^ pswz)) = pk;
      }
      const bf16x8 ap0 = *(const bf16x8*)(psrow + ((g * 16) ^ pswz));
      const bf16x8 ap1 = *(const bf16x8*)(psrow + ((64 + g * 16) ^ pswz));
      // O^T += V^T * P^T
      __builtin_amdgcn_s_setprio(1);
#pragma unroll
      for (int nt = 0; nt < 4; ++nt) {
        const bf16x8 bv0 = *swz_cptr(&Vs[cur][0][0], nt * 16 + li, g * 16);
        const bf16x8 bv1 = *swz_cptr(&Vs[cur][0][0], nt * 16 + li, 64 + g * 16);
        accO[u][nt] = MFMA(bv0, ap0, accO[u][nt]);
        accO[u][nt] = MFMA(bv1, ap1, accO[u][nt]);
      }
      __builtin_amdgcn_s_setprio(0);
    }
    // write next tile's staged regs into the other buffer (before next barrier)
    if (pf) {
      *swz_ptr(&Ks[cur ^ 1][0][0], r_st, qu * 32) = nk0;
      *swz_ptr(&Ks[cur ^ 1][0][0], r_st, qu * 32 + 16) = nk1;
      *swz_ptr(&Vs[cur ^ 1][0][0], r_st, qu * 32) = nv0;
      *swz_ptr(&Vs[cur ^ 1][0][0], r_st, qu * 32 + 16) = nv1;
    }
  }
  // epilogue: PRE-SWIZZLED store for out_gemm (row&7 == li&7)
#pragma unroll
  for (int u = 0; u < 2; ++u) {
    const float inv = 1.0f / l_run[u];
    bf16_t* arow = attn + (size_t)(b * 2048 + rbase0 + u * 16 + li) * 512 + h * 64;
#pragma unroll
    for (int nt = 0; nt < 4; ++nt) {
      bf16x4 pk;
#pragma unroll
      for (int i = 0; i < 4; ++i) pk[i] = (bf16_t)(accO[u][nt][i] * inv);
      *(bf16x4*)&arow[8 * ((nt * 2 + (g >> 1)) ^ (li & 7)) + (g & 1) * 4] = pk;
    }
  }
}

// ---------------------------------------------------------------------------
// out_gemm v7: 2 forecast slices per block (A staged/read once, used twice).
// A = attn (pre-swizzled), B = BmatT (transposed, pre-swizzled).
// global_load_lds staging, linear LDS, swizzled reads.
// grid (64 m-tiles, 4 col-tiles, 4 nf-pairs)
// ---------------------------------------------------------------------------
__global__ __launch_bounds__(256, 2) void out_gemm(const bf16_t* __restrict__ A,
                                                   const bf16_t* __restrict__ BmatT,
                                                   const float* __restrict__ bo,
                                                   float* __restrict__ out) {
  __shared__ __align__(16) bf16_t As[128 * 64];
  __shared__ __align__(16) bf16_t Bs[2][128 * 64];
  const int tid = threadIdx.x;
  const int wave = tid >> 6, lane = tid & 63;
  const int g = lane >> 4, li = lane & 15;
  const int row0 = blockIdx.x * 128;
  const int col0 = blockIdx.y * 128;
  const int nf0 = blockIdx.z * 2;
  const int wm = (wave >> 1) * 64, wn = (wave & 1) * 64;
  f32x4 acc[2][4][4] = {};
  const bf16_t* asrc = A + (size_t)(row0 + wave * 32 + (lane >> 3)) * 512 + (lane & 7) * 8;
  const bf16_t* bsrc = BmatT + (size_t)nf0 * 512 * 512 +
                       (size_t)(col0 + wave * 32 + (lane >> 3)) * 512 + (lane & 7) * 8;
  bf16_t* adst = &As[wave * 32 * 64];
  bf16_t* bdst0 = &Bs[0][wave * 32 * 64];
  bf16_t* bdst1 = &Bs[1][wave * 32 * 64];
  for (int k0 = 0; k0 < 512; k0 += 64) {
#pragma unroll
    for (int c = 0; c < 4; ++c) {
      gload16(asrc + (size_t)c * 8 * 512 + k0, adst + c * 512);
      gload16(bsrc + (size_t)c * 8 * 512 + k0, bdst0 + c * 512);
      gload16(bsrc + 262144 + (size_t)c * 8 * 512 + k0, bdst1 + c * 512);
    }
    __syncthreads();
#pragma unroll
    for (int ks = 0; ks < 2; ++ks) {
      bf16x8 af[4];
#pragma unroll
      for (int mr = 0; mr < 4; ++mr)
        af[mr] = *swz_cptr(As, wm + mr * 16 + li, ks * 64 + g * 16);
#pragma unroll
      for (int f = 0; f < 2; ++f) {
        bf16x8 bfr[4];
#pragma unroll
        for (int nr = 0; nr < 4; ++nr)
          bfr[nr] = *swz_cptr(Bs[f], wn + nr * 16 + li, ks * 64 + g * 16);
#pragma unroll
        for (int mr = 0; mr < 4; ++mr)
#pragma unroll
          for (int nr = 0; nr < 4; ++nr)
            acc[f][mr][nr] = MFMA(af[mr], bfr[nr], acc[f][mr][nr]);
      }
    }
    __syncthreads();
  }
  const int bb = row0 >> 11;
#pragma unroll
  for (int f = 0; f < 2; ++f) {
    float* obase = out + ((size_t)(bb * 8 + nf0 + f)) * (2048 * 512);
#pragma unroll
    for (int nr = 0; nr < 4; ++nr) {
      const int c = col0 + wn + nr * 16 + li;
      const float bv = bo[c];
#pragma unroll
      for (int mr = 0; mr < 4; ++mr) {
#pragma unroll
        for (int i = 0; i < 4; ++i) {
          const int r = row0 + wm + mr * 16 + g * 4 + i;
          const int s = r & 2047;
          obase[(size_t)s * 512 + c] = acc[f][mr][nr][i] + bv;
        }
      }
    }
  }
}

// ---------------------------------------------------------------------------
extern "C" void kernel_launch(void* const* d_in, const int* in_sizes, int n_in,
                              void* d_out, int out_size, void* d_ws, size_t ws_size,
                              hipStream_t stream) {
  const float* query = (const float*)d_in[0];
  // d_in[1]=key, d_in[2]=value are unused by the reference forward.
  const float* Wqkv = (const float*)d_in[3];
  const float* bqkv = (const float*)d_in[4];
  const float* Wo = (const float*)d_in[5];
  const float* bo = (const float*)d_in[6];
  const float* Xi = (const float*)d_in[7];
  float* out = (float*)d_out;

  char* ws = (char*)d_ws;
  bf16_t* qw = (bf16_t*)(ws + 0);                 // [4][8][2048][64] bf16 = 8 MiB (pre-scaled)
  bf16_t* kw = (bf16_t*)(ws + 8388608);           // 8 MiB
  bf16_t* vt = (bf16_t*)(ws + 16777216);          // [4][8][64][2048] bf16 = 8 MiB (transposed)
  // Xb and attn SHARE this region: Xb consumed by qkv_gemm, then fattn
  // overwrites it with attn (sequential stream order makes this safe).
  bf16_t* Xb = (bf16_t*)(ws + 25165824);          // [8192][512] bf16 = 8 MiB (pre-swizzled)
  bf16_t* attn = (bf16_t*)(ws + 25165824);        // [8192][512] bf16 = 8 MiB (pre-swizzled)
  bf16_t* BmatT = (bf16_t*)(ws + 33554432);       // [8][512][512] bf16 = 4 MiB (T, pre-swizzled)
  float* pows = (float*)(ws + 37748736);          // [8][8][64][64] f32 = 1 MiB
  bf16_t* WT = (bf16_t*)(ws + 38797312);          // [1536][512] bf16 = 1.5 MiB (T, pre-swizzled)

  xconv<<<dim3(2048), dim3(256), 0, stream>>>(query, Xb);
  wconv<<<dim3(24, 8), dim3(256), 0, stream>>>(Wqkv, WT);
  build_powers<<<dim3(8), dim3(256), 0, stream>>>(Xi, pows);
  build_B<<<dim3(4, 8, 8), dim3(256), 0, stream>>>(pows, Wo, BmatT);
  qkv_gemm<<<dim3(64, 12), dim3(256), 0, stream>>>(Xb, WT, bqkv, qw, kw, vt);
  fattn<<<dim3(16, 8, 4), dim3(256), 0, stream>>>(qw, kw, vt, attn);
  out_gemm<<<dim3(64, 4, 4), dim3(256), 0, stream>>>(attn, BmatT, bo, out);
}

// Round 8
// 185.462 us; speedup vs baseline: 1.1158x; 1.1158x over previous
//
#include <hip/hip_runtime.h>
#include <math.h>

// Problem constants: N=4, L=2048, E=512, H=8, hd=64, FORECAST=8
// M = N*L = 8192 token rows.

#define NEGV -1e30f

typedef __bf16 bf16_t;
typedef __bf16 bf16x4 __attribute__((ext_vector_type(4)));
typedef __bf16 bf16x8 __attribute__((ext_vector_type(8)));
typedef float f32x4 __attribute__((ext_vector_type(4)));

#define MFMA(a, b, c) __builtin_amdgcn_mfma_f32_16x16x32_bf16((a), (b), (c), 0, 0, 0)

// 0.125 * log2(e): folded into Q so scores are already in log2 domain.
#define QSCALE 0.18033688011112042f

// Swizzled LDS access for [*][64]-bf16 tiles (row stride 128 B):
// byte = r*128 + (colbyte ^ ((r&7)<<4)).  Applied on BOTH write and read
// (fattn K/V), or on read-only when the source was PRE-swizzled (GEMMs).
__device__ __forceinline__ bf16x8* swz_ptr(bf16_t* base, int r, int cb) {
  return (bf16x8*)((char*)base + r * 128 + (cb ^ ((r & 7) << 4)));
}
__device__ __forceinline__ const bf16x8* swz_cptr(const bf16_t* base, int r, int cb) {
  return (const bf16x8*)((const char*)base + r * 128 + (cb ^ ((r & 7) << 4)));
}

// async global->LDS, 16 B per lane. LDS dest is wave-uniform base + lane*16;
// global src is per-lane.
__device__ __forceinline__ void gload16(const bf16_t* g, bf16_t* l) {
  __builtin_amdgcn_global_load_lds(
      (const __attribute__((address_space(1))) void*)g,
      (__attribute__((address_space(3))) void*)l, 16, 0, 0);
}

// Pre-swizzle: logical col c (0..63) of a row r stored at:
//   c' = (c & 7) | 8*(((c>>3) ^ (r & 7)) & 7)   [within each 64-col k-block]

// ---------------------------------------------------------------------------
// xconv: Xb[s][k] = bf16(X[s][k]), PRE-SWIZZLED within 64-col k-blocks.
// ---------------------------------------------------------------------------
__global__ __launch_bounds__(256) void xconv(const float* __restrict__ X,
                                             bf16_t* __restrict__ Xb) {
  const int gid = blockIdx.x * 256 + threadIdx.x;
  const int s = gid >> 6, j = gid & 63;  // j: 8-elem block index within row
  const float4* src = (const float4*)(X + (size_t)s * 512 + j * 8);
  const float4 f0 = src[0], f1 = src[1];
  bf16x8 v;
  v[0] = (bf16_t)f0.x; v[1] = (bf16_t)f0.y; v[2] = (bf16_t)f0.z; v[3] = (bf16_t)f0.w;
  v[4] = (bf16_t)f1.x; v[5] = (bf16_t)f1.y; v[6] = (bf16_t)f1.z; v[7] = (bf16_t)f1.w;
  *(bf16x8*)&Xb[(size_t)s * 512 + (j >> 3) * 64 + 8 * ((j & 7) ^ (s & 7))] = v;
}

// ---------------------------------------------------------------------------
// wconv: WT[n][k] = bf16(Wqkv[k][n]), transposed + PRE-SWIZZLED.
// grid (24 n-tiles, 8 k-tiles).
// ---------------------------------------------------------------------------
__global__ __launch_bounds__(256) void wconv(const float* __restrict__ W,
                                             bf16_t* __restrict__ WT) {
  const int n0 = blockIdx.x * 64, k0 = blockIdx.y * 64;
  __shared__ float Wf[64][65];
  const int tid = threadIdx.x;
#pragma unroll
  for (int c = 0; c < 16; ++c) {
    const int idx = tid + c * 256;
    const int kk = idx >> 6, nn = idx & 63;
    Wf[kk][nn] = W[(size_t)(k0 + kk) * 1536 + n0 + nn];
  }
  __syncthreads();
  const int nr = tid >> 2;
  const int jb = (tid & 3) * 2;
#pragma unroll
  for (int t = 0; t < 2; ++t) {
    const int j = jb + t;
    bf16x8 v;
#pragma unroll
    for (int i = 0; i < 8; ++i) v[i] = (bf16_t)Wf[j * 8 + i][nr];
    *(bf16x8*)&WT[(size_t)(n0 + nr) * 512 + k0 + 8 * (j ^ (nr & 7))] = v;
  }
}

// ---------------------------------------------------------------------------
// build_powers: per head h, P = I + (Xi - Xi^T); pows[h][n] = P^(n+1), f32.
// ---------------------------------------------------------------------------
__global__ __launch_bounds__(256) void build_powers(const float* __restrict__ Xi,
                                                    float* __restrict__ pows) {
  const int h = blockIdx.x;
  __shared__ __align__(16) float P[64][68];
  __shared__ __align__(16) float cur[64][68];
  const int tid = threadIdx.x;
  const float* xi = Xi + (size_t)h * 4096;
  float* dst = pows + (size_t)h * 8 * 4096;
  for (int idx = tid; idx < 4096; idx += 256) {
    const int i = idx >> 6, j = idx & 63;
    const float p = (i == j ? 1.f : 0.f) + xi[i * 64 + j] - xi[j * 64 + i];
    P[i][j] = p;
    cur[i][j] = p;
    dst[idx] = p;  // n=0 -> P^1
  }
  __syncthreads();
  const int i = tid >> 2;
  const int j0 = (tid & 3) * 16;
  for (int n = 1; n < 8; ++n) {
    float a[16];
#pragma unroll
    for (int jj = 0; jj < 16; ++jj) a[jj] = 0.f;
    for (int dd = 0; dd < 64; ++dd) {
      const float c = cur[i][dd];
#pragma unroll
      for (int jj = 0; jj < 16; ++jj) a[jj] += c * P[dd][j0 + jj];
    }
    __syncthreads();
#pragma unroll
    for (int jj = 0; jj < 16; ++jj) {
      cur[i][j0 + jj] = a[jj];
      dst[n * 4096 + i * 64 + j0 + jj] = a[jj];
    }
    __syncthreads();
  }
}

// ---------------------------------------------------------------------------
// build_B: BmatT[n][e][(h*64+d)] = sum_dd pows[h][n][d][dd] * Wo[h*64+dd][e]
// Output TRANSPOSED [e][k] and PRE-SWIZZLED within each head's 64-col block.
// grid (4 e-tiles, 8 n, 8 h).
// ---------------------------------------------------------------------------
__global__ __launch_bounds__(256) void build_B(const float* __restrict__ pows,
                                               const float* __restrict__ Wo,
                                               bf16_t* __restrict__ BmatT) {
  const int et = blockIdx.x;
  const int n = blockIdx.y;
  const int h = blockIdx.z;
  __shared__ __align__(16) float P[64][68];
  __shared__ __align__(16) float We[64][128];
  const int tid = threadIdx.x;
  const float* src = pows + ((size_t)h * 8 + n) * 4096;
  for (int idx = tid; idx < 4096; idx += 256) P[idx >> 6][idx & 63] = src[idx];
  const int e0 = et * 128;
  for (int idx = tid; idx < 8192; idx += 256) {
    const int dd = idx >> 7, e = idx & 127;
    We[dd][e] = Wo[(size_t)(h * 64 + dd) * 512 + e0 + e];
  }
  __syncthreads();
  const int d = tid >> 2;
  const int eq = (tid & 3) * 32;  // multiple of 32 -> (e&7) == (j&7)
  float acc[32];
#pragma unroll
  for (int j = 0; j < 32; ++j) acc[j] = 0.f;
  for (int dd = 0; dd < 64; ++dd) {
    const float p = P[d][dd];
#pragma unroll
    for (int j = 0; j < 32; ++j) acc[j] += p * We[dd][eq + j];
  }
  bf16_t* dst = BmatT + (size_t)n * 512 * 512 + (size_t)(e0 + eq) * 512 + h * 64;
  const int dlo = d & 7, dhi = d >> 3;
#pragma unroll
  for (int j = 0; j < 32; ++j)
    dst[(size_t)j * 512 + 8 * (dhi ^ (j & 7)) + dlo] = (bf16_t)acc[j];
}

// ---------------------------------------------------------------------------
// qkv_gemm: qkv = X @ Wqkv + bqkv; A=Xb (pre-swizzled bf16), B=WT (transposed,
// pre-swizzled bf16). global_load_lds staging, linear LDS, swizzled reads.
// ---------------------------------------------------------------------------
__global__ __launch_bounds__(256) void qkv_gemm(const bf16_t* __restrict__ Xb,
                                                const bf16_t* __restrict__ WT,
                                                const float* __restrict__ bias,
                                                bf16_t* __restrict__ qw,
                                                bf16_t* __restrict__ kw,
                                                bf16_t* __restrict__ vt) {
  __shared__ __align__(16) bf16_t As[128 * 64];
  __shared__ __align__(16) bf16_t Bs[128 * 64];
  const int tid = threadIdx.x;
  const int wave = tid >> 6, lane = tid & 63;
  const int g = lane >> 4, li = lane & 15;
  const int row0 = blockIdx.x * 128;
  const int col0 = blockIdx.y * 128;
  const int wm = (wave >> 1) * 64, wn = (wave & 1) * 64;
  f32x4 acc[4][4] = {};
  const bf16_t* asrc = Xb + (size_t)(row0 + wave * 32 + (lane >> 3)) * 512 + (lane & 7) * 8;
  const bf16_t* bsrc = WT + (size_t)(col0 + wave * 32 + (lane >> 3)) * 512 + (lane & 7) * 8;
  bf16_t* adst = &As[wave * 32 * 64];
  bf16_t* bdst = &Bs[wave * 32 * 64];
  for (int k0 = 0; k0 < 512; k0 += 64) {
#pragma unroll
    for (int c = 0; c < 4; ++c) {
      gload16(asrc + (size_t)c * 8 * 512 + k0, adst + c * 512);
      gload16(bsrc + (size_t)c * 8 * 512 + k0, bdst + c * 512);
    }
    __syncthreads();
#pragma unroll
    for (int ks = 0; ks < 2; ++ks) {
      bf16x8 af[4], bfr[4];
#pragma unroll
      for (int mr = 0; mr < 4; ++mr)
        af[mr] = *swz_cptr(As, wm + mr * 16 + li, ks * 64 + g * 16);
#pragma unroll
      for (int nr = 0; nr < 4; ++nr)
        bfr[nr] = *swz_cptr(Bs, wn + nr * 16 + li, ks * 64 + g * 16);
#pragma unroll
      for (int mr = 0; mr < 4; ++mr)
#pragma unroll
        for (int nr = 0; nr < 4; ++nr)
          acc[mr][nr] = MFMA(af[mr], bfr[nr], acc[mr][nr]);
    }
    __syncthreads();
  }
  // epilogue
  const int cbase = col0 + wn;            // multiple of 64
  const int sel = cbase >> 9;             // 0=q 1=k 2=v (uniform per wave)
  const int hh = (cbase & 511) >> 6;      // head (uniform per wave)
  const int bb = row0 >> 11;              // batch (uniform per block)
  const size_t hb = (size_t)(bb * 8 + hh) * (2048 * 64);
  if (sel == 2) {
    // v: transposed store vt[d][s], packed bf16x4 along s
    bf16_t* vbase = vt + hb;
#pragma unroll
    for (int nr = 0; nr < 4; ++nr) {
      const int dcol = nr * 16 + li;
      const float bv = bias[cbase + dcol];
#pragma unroll
      for (int mr = 0; mr < 4; ++mr) {
        bf16x4 pk;
#pragma unroll
        for (int i = 0; i < 4; ++i) pk[i] = (bf16_t)(acc[mr][nr][i] + bv);
        const int s = (row0 + wm + mr * 16 + g * 4) & 2047;
        *(bf16x4*)&vbase[(size_t)dcol * 2048 + s] = pk;
      }
    }
  } else {
    bf16_t* dstp = (sel == 0 ? qw : kw) + hb;
    const float sc = (sel == 0) ? QSCALE : 1.0f;
#pragma unroll
    for (int nr = 0; nr < 4; ++nr) {
      const int dcol = nr * 16 + li;
      const float bv = bias[cbase + dcol];
#pragma unroll
      for (int mr = 0; mr < 4; ++mr) {
#pragma unroll
        for (int i = 0; i < 4; ++i) {
          const int r = row0 + wm + mr * 16 + g * 4 + i;
          const int s = r & 2047;
          dstp[(size_t)s * 64 + dcol] = (bf16_t)((acc[mr][nr][i] + bv) * sc);
        }
      }
    }
  }
}

// ---------------------------------------------------------------------------
// fattn v8: QBLK=64 swapped-operand layout (r6 structure) + SPLIT-K for long
// q-tiles. blockIdx.x in [0,48):
//   x in [ 0,16): qt = 31-x,  K-tiles [0,16)    -> partial chunk 0 (no mask)
//   x in [16,32): qt = 47-x,  K-tiles [16,qt+1) -> partial chunk 1 (diag)
//   x in [32,48): qt = 47-x,  K-tiles [0,qt+1)  -> final (qt < 16)
// Every block does <= 16 K-tile visits -> balanced; 1536 blocks.
// Partials: unnormalized O^T (f32) + per-row (m,l) in log2 domain.
// ---------------------------------------------------------------------------
__global__ __launch_bounds__(256) void fattn(const bf16_t* __restrict__ qw,
                                             const bf16_t* __restrict__ kw,
                                             const bf16_t* __restrict__ vt,
                                             bf16_t* __restrict__ attn,
                                             float* __restrict__ opart,
                                             float* __restrict__ ml) {
  __shared__ __align__(16) bf16_t Ks[2][64][64];
  __shared__ __align__(16) bf16_t Vs[2][64][64];  // rows = d, cols = key
  __shared__ __align__(16) bf16_t Ps[4][16][64];  // wave-private P^T source, swizzled
  const int tid = threadIdx.x;
  const int w = tid >> 6;
  const int lane = tid & 63;
  const int g = lane >> 4;
  const int li = lane & 15;
  const int x = blockIdx.x;
  int qt, ktb, kte, chunk;
  bool split;
  if (x < 16) {
    qt = 31 - x; ktb = 0; kte = 16; chunk = 0; split = true;
  } else if (x < 32) {
    qt = 47 - x; ktb = 16; kte = qt + 1; chunk = 1; split = true;
  } else {
    qt = 47 - x; ktb = 0; kte = qt + 1; chunk = 0; split = false;
  }
  const int h = blockIdx.y;
  const int b = blockIdx.z;
  const size_t base = ((size_t)(b * 8 + h)) * (2048 * 64);
  const int q0 = qt * 64;
  const int qrow = q0 + w * 16 + li;  // this lane's q-row
  const bf16x8 aq0 = *(const bf16x8*)(qw + base + (size_t)qrow * 64 + g * 8);
  const bf16x8 aq1 = *(const bf16x8*)(qw + base + (size_t)qrow * 64 + 32 + g * 8);
  const bf16_t* kbase = kw + base;
  const bf16_t* vbase = vt + base;  // [64][2048]
  const int r_st = tid >> 2;  // staging row 0..63
  const int qu = tid & 3;     // staging quarter
  // prologue: stage tile ktb into buffer 0 (swizzled)
  {
    const bf16_t* kp = kbase + (size_t)(ktb * 64 + r_st) * 64 + qu * 16;
    const bf16_t* vp = vbase + (size_t)r_st * 2048 + ktb * 64 + qu * 16;
    *swz_ptr(&Ks[0][0][0], r_st, qu * 32) = *(const bf16x8*)kp;
    *swz_ptr(&Ks[0][0][0], r_st, qu * 32 + 16) = *(const bf16x8*)(kp + 8);
    *swz_ptr(&Vs[0][0][0], r_st, qu * 32) = *(const bf16x8*)vp;
    *swz_ptr(&Vs[0][0][0], r_st, qu * 32 + 16) = *(const bf16x8*)(vp + 8);
  }
  f32x4 accO[4] = {};  // accO[nt][i] = O^T: q=li, d = nt*16 + g*4 + i
  float m_run = -__builtin_inff();
  float l_run = 0.f;
  // P-row LDS addressing (wave-private, swizzled by (li&7))
  char* const psrow = (char*)&Ps[w][li][0];
  const int pswz = (li & 7) << 4;
  for (int kt = ktb; kt < kte; ++kt) {
    __syncthreads();  // buf[cur] fully staged; previous compute done
    const int cur = (kt - ktb) & 1;
    const bool pf = (kt + 1) < kte;
    // T14: issue next tile's global loads now; they land during the MFMA phase
    bf16x8 nk0, nk1, nv0, nv1;
    if (pf) {
      const int kb2 = (kt + 1) * 64;
      const bf16_t* kp = kbase + (size_t)(kb2 + r_st) * 64 + qu * 16;
      const bf16_t* vp = vbase + (size_t)r_st * 2048 + kb2 + qu * 16;
      nk0 = *(const bf16x8*)kp;
      nk1 = *(const bf16x8*)(kp + 8);
      nv0 = *(const bf16x8*)vp;
      nv1 = *(const bf16x8*)(vp + 8);
    }
    // S^T tile: sv[nt][i] = S[q = li][key = kb + nt*16 + g*4 + i]
    f32x4 sv[4];
    __builtin_amdgcn_s_setprio(1);
#pragma unroll
    for (int nt = 0; nt < 4; ++nt) {
      const bf16x8 bk0 = *swz_cptr(&Ks[cur][0][0], nt * 16 + li, g * 16);
      const bf16x8 bk1 = *swz_cptr(&Ks[cur][0][0], nt * 16 + li, 64 + g * 16);
      f32x4 z = {0.f, 0.f, 0.f, 0.f};
      z = MFMA(bk0, aq0, z);
      sv[nt] = MFMA(bk1, aq1, z);
    }
    __builtin_amdgcn_s_setprio(0);
    if (kt == qt) {  // diagonal tile mask: key > q-row
#pragma unroll
      for (int nt = 0; nt < 4; ++nt)
#pragma unroll
        for (int i = 0; i < 4; ++i)
          if (nt * 16 + g * 4 + i > w * 16 + li) sv[nt][i] = NEGV;
    }
    // row max: 15 in-lane + 2 shuffles
    float pmax = sv[0][0];
#pragma unroll
    for (int nt = 0; nt < 4; ++nt)
#pragma unroll
      for (int i = 0; i < 4; ++i) pmax = fmaxf(pmax, sv[nt][i]);
    pmax = fmaxf(pmax, __shfl_xor(pmax, 16, 64));
    pmax = fmaxf(pmax, __shfl_xor(pmax, 32, 64));
    // T13 defer-max: only rescale when max grew by > 8 (log2 domain)
    if (!__all(pmax - m_run <= 8.f)) {
      const float newm = fmaxf(m_run, pmax);
      const float sc = exp2f(m_run - newm);
      l_run *= sc;
      m_run = newm;
#pragma unroll
      for (int nt = 0; nt < 4; ++nt)
#pragma unroll
        for (int i = 0; i < 4; ++i) accO[nt][i] *= sc;
    }
    // P = exp2(S - m), in-lane sum + 2 shuffles
    float rsum = 0.f;
#pragma unroll
    for (int nt = 0; nt < 4; ++nt) {
#pragma unroll
      for (int i = 0; i < 4; ++i) {
        const float p = exp2f(sv[nt][i] - m_run);
        sv[nt][i] = p;
        rsum += p;
      }
    }
    rsum += __shfl_xor(rsum, 16, 64);
    rsum += __shfl_xor(rsum, 32, 64);
    l_run += rsum;
    // P -> wave-private LDS, packed bf16x4, XOR-swizzled (4 x ds_write_b64)
#pragma unroll
    for (int nt = 0; nt < 4; ++nt) {
      bf16x4 pk;
#pragma unroll
      for (int i = 0; i < 4; ++i) pk[i] = (bf16_t)sv[nt][i];
      *(bf16x4*)(psrow + ((nt * 32 + g * 8) ^ pswz)) = pk;
    }
    const bf16x8 ap0 = *(const bf16x8*)(psrow + ((g * 16) ^ pswz));
    const bf16x8 ap1 = *(const bf16x8*)(psrow + ((64 + g * 16) ^ pswz));
    // O^T += V^T * P^T
    __builtin_amdgcn_s_setprio(1);
#pragma unroll
    for (int nt = 0; nt < 4; ++nt) {
      const bf16x8 bv0 = *swz_cptr(&Vs[cur][0][0], nt * 16 + li, g * 16);
      const bf16x8 bv1 = *swz_cptr(&Vs[cur][0][0], nt * 16 + li, 64 + g * 16);
      accO[nt] = MFMA(bv0, ap0, accO[nt]);
      accO[nt] = MFMA(bv1, ap1, accO[nt]);
    }
    __builtin_amdgcn_s_setprio(0);
    // write next tile's staged regs into the other buffer (before next barrier)
    if (pf) {
      *swz_ptr(&Ks[cur ^ 1][0][0], r_st, qu * 32) = nk0;
      *swz_ptr(&Ks[cur ^ 1][0][0], r_st, qu * 32 + 16) = nk1;
      *swz_ptr(&Vs[cur ^ 1][0][0], r_st, qu * 32) = nv0;
      *swz_ptr(&Vs[cur ^ 1][0][0], r_st, qu * 32 + 16) = nv1;
    }
  }
  if (!split) {
    // final: normalized, PRE-SWIZZLED store for out_gemm (row&7 == li&7)
    const float inv = 1.0f / l_run;
    bf16_t* arow = attn + (size_t)(b * 2048 + qrow) * 512 + h * 64;
#pragma unroll
    for (int nt = 0; nt < 4; ++nt) {
      bf16x4 pk;
#pragma unroll
      for (int i = 0; i < 4; ++i) pk[i] = (bf16_t)(accO[nt][i] * inv);
      *(bf16x4*)&arow[8 * ((nt * 2 + (g >> 1)) ^ (li & 7)) + (g & 1) * 4] = pk;
    }
  } else {
    // partial: unnormalized O^T f32 + (m, l) per row
    const int row = w * 16 + li;
    const size_t pbase = (((size_t)(b * 8 + h) * 16 + (qt - 16)) * 2 + chunk) * 64 + row;
    float* op = opart + pbase * 64;
#pragma unroll
    for (int nt = 0; nt < 4; ++nt) *(f32x4*)&op[nt * 16 + g * 4] = accO[nt];
    if (g == 0) {
      ml[pbase * 2] = m_run;
      ml[pbase * 2 + 1] = l_run;
    }
  }
}

// ---------------------------------------------------------------------------
// fcombine: merge the two split-K partials for qt in [16,32) and write the
// normalized, pre-swizzled attn rows. grid (16 qt, 8 h, 4 b), 256 threads.
// ---------------------------------------------------------------------------
__global__ __launch_bounds__(256) void fcombine(const float* __restrict__ opart,
                                                const float* __restrict__ ml,
                                                bf16_t* __restrict__ attn) {
  const int qi = blockIdx.x;  // qt = 16 + qi
  const int h = blockIdx.y;
  const int b = blockIdx.z;
  const int tid = threadIdx.x;
  const int row = tid >> 2;
  const int dq = (tid & 3) * 16;
  const size_t base2 = ((size_t)(b * 8 + h) * 16 + qi) * 2;
  const size_t p0 = (base2 * 64 + row);
  const size_t p1 = ((base2 + 1) * 64 + row);
  const float m1 = ml[p0 * 2], l1 = ml[p0 * 2 + 1];
  const float m2 = ml[p1 * 2], l2 = ml[p1 * 2 + 1];
  const float m = fmaxf(m1, m2);
  const float w1 = exp2f(m1 - m), w2 = exp2f(m2 - m);
  const float inv = 1.0f / (l1 * w1 + l2 * w2);
  const float* o1 = opart + p0 * 64;
  const float* o2 = opart + p1 * 64;
  const int qrow = (16 + qi) * 64 + row;
  bf16_t* arow = attn + (size_t)(b * 2048 + qrow) * 512 + h * 64;
#pragma unroll
  for (int t = 0; t < 2; ++t) {
    const int c0 = dq + t * 8;
    const f32x4 a1 = *(const f32x4*)&o1[c0];
    const f32x4 b1 = *(const f32x4*)&o1[c0 + 4];
    const f32x4 a2 = *(const f32x4*)&o2[c0];
    const f32x4 b2 = *(const f32x4*)&o2[c0 + 4];
    bf16x8 v;
#pragma unroll
    for (int i = 0; i < 4; ++i) {
      v[i] = (bf16_t)((a1[i] * w1 + a2[i] * w2) * inv);
      v[4 + i] = (bf16_t)((b1[i] * w1 + b2[i] * w2) * inv);
    }
    *(bf16x8*)&arow[8 * ((c0 >> 3) ^ (row & 7))] = v;
  }
}

// ---------------------------------------------------------------------------
// out_gemm: 2 forecast slices per block (A staged/read once, used twice).
// A = attn (pre-swizzled), B = BmatT (transposed, pre-swizzled).
// global_load_lds staging, linear LDS, swizzled reads.
// grid (64 m-tiles, 4 col-tiles, 4 nf-pairs)
// ---------------------------------------------------------------------------
__global__ __launch_bounds__(256, 2) void out_gemm(const bf16_t* __restrict__ A,
                                                   const bf16_t* __restrict__ BmatT,
                                                   const float* __restrict__ bo,
                                                   float* __restrict__ out) {
  __shared__ __align__(16) bf16_t As[128 * 64];
  __shared__ __align__(16) bf16_t Bs[2][128 * 64];
  const int tid = threadIdx.x;
  const int wave = tid >> 6, lane = tid & 63;
  const int g = lane >> 4, li = lane & 15;
  const int row0 = blockIdx.x * 128;
  const int col0 = blockIdx.y * 128;
  const int nf0 = blockIdx.z * 2;
  const int wm = (wave >> 1) * 64, wn = (wave & 1) * 64;
  f32x4 acc[2][4][4] = {};
  const bf16_t* asrc = A + (size_t)(row0 + wave * 32 + (lane >> 3)) * 512 + (lane & 7) * 8;
  const bf16_t* bsrc = BmatT + (size_t)nf0 * 512 * 512 +
                       (size_t)(col0 + wave * 32 + (lane >> 3)) * 512 + (lane & 7) * 8;
  bf16_t* adst = &As[wave * 32 * 64];
  bf16_t* bdst0 = &Bs[0][wave * 32 * 64];
  bf16_t* bdst1 = &Bs[1][wave * 32 * 64];
  for (int k0 = 0; k0 < 512; k0 += 64) {
#pragma unroll
    for (int c = 0; c < 4; ++c) {
      gload16(asrc + (size_t)c * 8 * 512 + k0, adst + c * 512);
      gload16(bsrc + (size_t)c * 8 * 512 + k0, bdst0 + c * 512);
      gload16(bsrc + 262144 + (size_t)c * 8 * 512 + k0, bdst1 + c * 512);
    }
    __syncthreads();
#pragma unroll
    for (int ks = 0; ks < 2; ++ks) {
      bf16x8 af[4];
#pragma unroll
      for (int mr = 0; mr < 4; ++mr)
        af[mr] = *swz_cptr(As, wm + mr * 16 + li, ks * 64 + g * 16);
#pragma unroll
      for (int f = 0; f < 2; ++f) {
        bf16x8 bfr[4];
#pragma unroll
        for (int nr = 0; nr < 4; ++nr)
          bfr[nr] = *swz_cptr(Bs[f], wn + nr * 16 + li, ks * 64 + g * 16);
#pragma unroll
        for (int mr = 0; mr < 4; ++mr)
#pragma unroll
          for (int nr = 0; nr < 4; ++nr)
            acc[f][mr][nr] = MFMA(af[mr], bfr[nr], acc[f][mr][nr]);
      }
    }
    __syncthreads();
  }
  const int bb = row0 >> 11;
#pragma unroll
  for (int f = 0; f < 2; ++f) {
    float* obase = out + ((size_t)(bb * 8 + nf0 + f)) * (2048 * 512);
#pragma unroll
    for (int nr = 0; nr < 4; ++nr) {
      const int c = col0 + wn + nr * 16 + li;
      const float bv = bo[c];
#pragma unroll
      for (int mr = 0; mr < 4; ++mr) {
#pragma unroll
        for (int i = 0; i < 4; ++i) {
          const int r = row0 + wm + mr * 16 + g * 4 + i;
          const int s = r & 2047;
          obase[(size_t)s * 512 + c] = acc[f][mr][nr][i] + bv;
        }
      }
    }
  }
}

// ---------------------------------------------------------------------------
extern "C" void kernel_launch(void* const* d_in, const int* in_sizes, int n_in,
                              void* d_out, int out_size, void* d_ws, size_t ws_size,
                              hipStream_t stream) {
  const float* query = (const float*)d_in[0];
  // d_in[1]=key, d_in[2]=value are unused by the reference forward.
  const float* Wqkv = (const float*)d_in[3];
  const float* bqkv = (const float*)d_in[4];
  const float* Wo = (const float*)d_in[5];
  const float* bo = (const float*)d_in[6];
  const float* Xi = (const float*)d_in[7];
  float* out = (float*)d_out;

  char* ws = (char*)d_ws;
  bf16_t* qw = (bf16_t*)(ws + 0);                 // [4][8][2048][64] bf16 = 8 MiB (pre-scaled)
  bf16_t* kw = (bf16_t*)(ws + 8388608);           // 8 MiB
  bf16_t* vt = (bf16_t*)(ws + 16777216);          // [4][8][64][2048] bf16 = 8 MiB (transposed)
  // Xb and attn SHARE this region: Xb consumed by qkv_gemm, then fattn
  // overwrites it with attn (sequential stream order makes this safe).
  bf16_t* Xb = (bf16_t*)(ws + 25165824);          // [8192][512] bf16 = 8 MiB (pre-swizzled)
  bf16_t* attn = (bf16_t*)(ws + 25165824);        // [8192][512] bf16 = 8 MiB (pre-swizzled)
  bf16_t* BmatT = (bf16_t*)(ws + 33554432);       // [8][512][512] bf16 = 4 MiB (T, pre-swizzled)
  float* pows = (float*)(ws + 37748736);          // [8][8][64][64] f32 = 1 MiB
  bf16_t* WT = (bf16_t*)(ws + 38797312);          // [1536][512] bf16 = 1.5 MiB (T, pre-swizzled)
  float* opart = (float*)(ws + 40370176);         // [32][16][2][64][64] f32 = 16 MiB
  float* mlbuf = (float*)(ws + 57147392);         // [32][16][2][64][2] f32 = 512 KiB

  xconv<<<dim3(2048), dim3(256), 0, stream>>>(query, Xb);
  wconv<<<dim3(24, 8), dim3(256), 0, stream>>>(Wqkv, WT);
  build_powers<<<dim3(8), dim3(256), 0, stream>>>(Xi, pows);
  build_B<<<dim3(4, 8, 8), dim3(256), 0, stream>>>(pows, Wo, BmatT);
  qkv_gemm<<<dim3(64, 12), dim3(256), 0, stream>>>(Xb, WT, bqkv, qw, kw, vt);
  fattn<<<dim3(48, 8, 4), dim3(256), 0, stream>>>(qw, kw, vt, attn, opart, mlbuf);
  fcombine<<<dim3(16, 8, 4), dim3(256), 0, stream>>>(opart, mlbuf, attn);
  out_gemm<<<dim3(64, 4, 4), dim3(256), 0, stream>>>(attn, BmatT, bo, out);
}

// Round 9
// 183.715 us; speedup vs baseline: 1.1264x; 1.0095x over previous
//
#include <hip/hip_runtime.h>
#include <math.h>

// Problem constants: N=4, L=2048, E=512, H=8, hd=64, FORECAST=8
// M = N*L = 8192 token rows.

#define NEGV -1e30f

typedef __bf16 bf16_t;
typedef __bf16 bf16x4 __attribute__((ext_vector_type(4)));
typedef __bf16 bf16x8 __attribute__((ext_vector_type(8)));
typedef float f32x4 __attribute__((ext_vector_type(4)));

#define MFMA(a, b, c) __builtin_amdgcn_mfma_f32_16x16x32_bf16((a), (b), (c), 0, 0, 0)

// 0.125 * log2(e): folded into Q so scores are already in log2 domain.
#define QSCALE 0.18033688011112042f

// Swizzled LDS access for [*][64]-bf16 tiles (row stride 128 B):
// byte = r*128 + (colbyte ^ ((r&7)<<4)).  Applied on BOTH write and read
// (fattn K/V), or on read-only when the source was PRE-swizzled (GEMMs).
__device__ __forceinline__ bf16x8* swz_ptr(bf16_t* base, int r, int cb) {
  return (bf16x8*)((char*)base + r * 128 + (cb ^ ((r & 7) << 4)));
}
__device__ __forceinline__ const bf16x8* swz_cptr(const bf16_t* base, int r, int cb) {
  return (const bf16x8*)((const char*)base + r * 128 + (cb ^ ((r & 7) << 4)));
}

// async global->LDS, 16 B per lane. LDS dest is wave-uniform base + lane*16;
// global src is per-lane.
__device__ __forceinline__ void gload16(const bf16_t* g, bf16_t* l) {
  __builtin_amdgcn_global_load_lds(
      (const __attribute__((address_space(1))) void*)g,
      (__attribute__((address_space(3))) void*)l, 16, 0, 0);
}

// Pre-swizzle: logical col c (0..63) of a row r stored at:
//   c' = (c & 7) | 8*(((c>>3) ^ (r & 7)) & 7)   [within each 64-col k-block]

// ---------------------------------------------------------------------------
// xconv: Xb[s][k] = bf16(X[s][k]), PRE-SWIZZLED within 64-col k-blocks.
// ---------------------------------------------------------------------------
__global__ __launch_bounds__(256) void xconv(const float* __restrict__ X,
                                             bf16_t* __restrict__ Xb) {
  const int gid = blockIdx.x * 256 + threadIdx.x;
  const int s = gid >> 6, j = gid & 63;  // j: 8-elem block index within row
  const float4* src = (const float4*)(X + (size_t)s * 512 + j * 8);
  const float4 f0 = src[0], f1 = src[1];
  bf16x8 v;
  v[0] = (bf16_t)f0.x; v[1] = (bf16_t)f0.y; v[2] = (bf16_t)f0.z; v[3] = (bf16_t)f0.w;
  v[4] = (bf16_t)f1.x; v[5] = (bf16_t)f1.y; v[6] = (bf16_t)f1.z; v[7] = (bf16_t)f1.w;
  *(bf16x8*)&Xb[(size_t)s * 512 + (j >> 3) * 64 + 8 * ((j & 7) ^ (s & 7))] = v;
}

// ---------------------------------------------------------------------------
// wconv: WT[n][k] = bf16(Wqkv[k][n]), transposed + PRE-SWIZZLED.
// grid (24 n-tiles, 8 k-tiles).
// ---------------------------------------------------------------------------
__global__ __launch_bounds__(256) void wconv(const float* __restrict__ W,
                                             bf16_t* __restrict__ WT) {
  const int n0 = blockIdx.x * 64, k0 = blockIdx.y * 64;
  __shared__ float Wf[64][65];
  const int tid = threadIdx.x;
#pragma unroll
  for (int c = 0; c < 16; ++c) {
    const int idx = tid + c * 256;
    const int kk = idx >> 6, nn = idx & 63;
    Wf[kk][nn] = W[(size_t)(k0 + kk) * 1536 + n0 + nn];
  }
  __syncthreads();
  const int nr = tid >> 2;
  const int jb = (tid & 3) * 2;
#pragma unroll
  for (int t = 0; t < 2; ++t) {
    const int j = jb + t;
    bf16x8 v;
#pragma unroll
    for (int i = 0; i < 8; ++i) v[i] = (bf16_t)Wf[j * 8 + i][nr];
    *(bf16x8*)&WT[(size_t)(n0 + nr) * 512 + k0 + 8 * (j ^ (nr & 7))] = v;
  }
}

// ---------------------------------------------------------------------------
// build_powers: per head h, P = I + (Xi - Xi^T); pows[h][n] = P^(n+1), f32.
// ---------------------------------------------------------------------------
__global__ __launch_bounds__(256) void build_powers(const float* __restrict__ Xi,
                                                    float* __restrict__ pows) {
  const int h = blockIdx.x;
  __shared__ __align__(16) float P[64][68];
  __shared__ __align__(16) float cur[64][68];
  const int tid = threadIdx.x;
  const float* xi = Xi + (size_t)h * 4096;
  float* dst = pows + (size_t)h * 8 * 4096;
  for (int idx = tid; idx < 4096; idx += 256) {
    const int i = idx >> 6, j = idx & 63;
    const float p = (i == j ? 1.f : 0.f) + xi[i * 64 + j] - xi[j * 64 + i];
    P[i][j] = p;
    cur[i][j] = p;
    dst[idx] = p;  // n=0 -> P^1
  }
  __syncthreads();
  const int i = tid >> 2;
  const int j0 = (tid & 3) * 16;
  for (int n = 1; n < 8; ++n) {
    float a[16];
#pragma unroll
    for (int jj = 0; jj < 16; ++jj) a[jj] = 0.f;
    for (int dd = 0; dd < 64; ++dd) {
      const float c = cur[i][dd];
#pragma unroll
      for (int jj = 0; jj < 16; ++jj) a[jj] += c * P[dd][j0 + jj];
    }
    __syncthreads();
#pragma unroll
    for (int jj = 0; jj < 16; ++jj) {
      cur[i][j0 + jj] = a[jj];
      dst[n * 4096 + i * 64 + j0 + jj] = a[jj];
    }
    __syncthreads();
  }
}

// ---------------------------------------------------------------------------
// build_B: BmatT[n][e][(h*64+d)] = sum_dd pows[h][n][d][dd] * Wo[h*64+dd][e]
// Output TRANSPOSED [e][k] and PRE-SWIZZLED within each head's 64-col block.
// grid (4 e-tiles, 8 n, 8 h).
// ---------------------------------------------------------------------------
__global__ __launch_bounds__(256) void build_B(const float* __restrict__ pows,
                                               const float* __restrict__ Wo,
                                               bf16_t* __restrict__ BmatT) {
  const int et = blockIdx.x;
  const int n = blockIdx.y;
  const int h = blockIdx.z;
  __shared__ __align__(16) float P[64][68];
  __shared__ __align__(16) float We[64][128];
  const int tid = threadIdx.x;
  const float* src = pows + ((size_t)h * 8 + n) * 4096;
  for (int idx = tid; idx < 4096; idx += 256) P[idx >> 6][idx & 63] = src[idx];
  const int e0 = et * 128;
  for (int idx = tid; idx < 8192; idx += 256) {
    const int dd = idx >> 7, e = idx & 127;
    We[dd][e] = Wo[(size_t)(h * 64 + dd) * 512 + e0 + e];
  }
  __syncthreads();
  const int d = tid >> 2;
  const int eq = (tid & 3) * 32;  // multiple of 32 -> (e&7) == (j&7)
  float acc[32];
#pragma unroll
  for (int j = 0; j < 32; ++j) acc[j] = 0.f;
  for (int dd = 0; dd < 64; ++dd) {
    const float p = P[d][dd];
#pragma unroll
    for (int j = 0; j < 32; ++j) acc[j] += p * We[dd][eq + j];
  }
  bf16_t* dst = BmatT + (size_t)n * 512 * 512 + (size_t)(e0 + eq) * 512 + h * 64;
  const int dlo = d & 7, dhi = d >> 3;
#pragma unroll
  for (int j = 0; j < 32; ++j)
    dst[(size_t)j * 512 + 8 * (dhi ^ (j & 7)) + dlo] = (bf16_t)acc[j];
}

// ---------------------------------------------------------------------------
// qkv_gemm v9: counted-vmcnt double-buffered gload_lds pipeline (T4).
// A=Xb (pre-swizzled bf16), B=WT (transposed, pre-swizzled bf16).
// Per K-step: stage next tile (8 gload_lds/wave) -> vmcnt(8) -> barrier ->
// compute current -> barrier. Stage latency hides under previous compute.
// ---------------------------------------------------------------------------
__global__ __launch_bounds__(256) void qkv_gemm(const bf16_t* __restrict__ Xb,
                                                const bf16_t* __restrict__ WT,
                                                const float* __restrict__ bias,
                                                bf16_t* __restrict__ qw,
                                                bf16_t* __restrict__ kw,
                                                bf16_t* __restrict__ vt) {
  __shared__ __align__(16) bf16_t As[2][128 * 64];
  __shared__ __align__(16) bf16_t Bs[2][128 * 64];
  const int tid = threadIdx.x;
  const int wave = tid >> 6, lane = tid & 63;
  const int g = lane >> 4, li = lane & 15;
  const int row0 = blockIdx.x * 128;
  const int col0 = blockIdx.y * 128;
  const int wm = (wave >> 1) * 64, wn = (wave & 1) * 64;
  f32x4 acc[4][4] = {};
  const bf16_t* asrc = Xb + (size_t)(row0 + wave * 32 + (lane >> 3)) * 512 + (lane & 7) * 8;
  const bf16_t* bsrc = WT + (size_t)(col0 + wave * 32 + (lane >> 3)) * 512 + (lane & 7) * 8;
  bf16_t* adst0 = &As[0][wave * 32 * 64];
  bf16_t* adst1 = &As[1][wave * 32 * 64];
  bf16_t* bdst0 = &Bs[0][wave * 32 * 64];
  bf16_t* bdst1 = &Bs[1][wave * 32 * 64];
  auto stage = [&](int bi, int kt) {
    const int k0 = kt * 64;
    bf16_t* ad = bi ? adst1 : adst0;
    bf16_t* bd = bi ? bdst1 : bdst0;
#pragma unroll
    for (int c = 0; c < 4; ++c) {
      gload16(asrc + (size_t)c * 8 * 512 + k0, ad + c * 512);
      gload16(bsrc + (size_t)c * 8 * 512 + k0, bd + c * 512);
    }
  };
  stage(0, 0);
#pragma unroll
  for (int t = 0; t < 8; ++t) {
    const int cur = t & 1;
    if (t < 7) {
      stage(cur ^ 1, t + 1);
      asm volatile("s_waitcnt vmcnt(8)" ::: "memory");
    } else {
      asm volatile("s_waitcnt vmcnt(0)" ::: "memory");
    }
    __builtin_amdgcn_s_barrier();
    __builtin_amdgcn_sched_barrier(0);
#pragma unroll
    for (int ks = 0; ks < 2; ++ks) {
      bf16x8 af[4], bfr[4];
#pragma unroll
      for (int mr = 0; mr < 4; ++mr)
        af[mr] = *swz_cptr(As[cur], wm + mr * 16 + li, ks * 64 + g * 16);
#pragma unroll
      for (int nr = 0; nr < 4; ++nr)
        bfr[nr] = *swz_cptr(Bs[cur], wn + nr * 16 + li, ks * 64 + g * 16);
#pragma unroll
      for (int mr = 0; mr < 4; ++mr)
#pragma unroll
        for (int nr = 0; nr < 4; ++nr)
          acc[mr][nr] = MFMA(af[mr], bfr[nr], acc[mr][nr]);
    }
    __builtin_amdgcn_s_barrier();
    __builtin_amdgcn_sched_barrier(0);
  }
  // epilogue
  const int cbase = col0 + wn;            // multiple of 64
  const int sel = cbase >> 9;             // 0=q 1=k 2=v (uniform per wave)
  const int hh = (cbase & 511) >> 6;      // head (uniform per wave)
  const int bb = row0 >> 11;              // batch (uniform per block)
  const size_t hb = (size_t)(bb * 8 + hh) * (2048 * 64);
  if (sel == 2) {
    // v: transposed store vt[d][s], packed bf16x4 along s
    bf16_t* vbase = vt + hb;
#pragma unroll
    for (int nr = 0; nr < 4; ++nr) {
      const int dcol = nr * 16 + li;
      const float bv = bias[cbase + dcol];
#pragma unroll
      for (int mr = 0; mr < 4; ++mr) {
        bf16x4 pk;
#pragma unroll
        for (int i = 0; i < 4; ++i) pk[i] = (bf16_t)(acc[mr][nr][i] + bv);
        const int s = (row0 + wm + mr * 16 + g * 4) & 2047;
        *(bf16x4*)&vbase[(size_t)dcol * 2048 + s] = pk;
      }
    }
  } else {
    bf16_t* dstp = (sel == 0 ? qw : kw) + hb;
    const float sc = (sel == 0) ? QSCALE : 1.0f;
#pragma unroll
    for (int nr = 0; nr < 4; ++nr) {
      const int dcol = nr * 16 + li;
      const float bv = bias[cbase + dcol];
#pragma unroll
      for (int mr = 0; mr < 4; ++mr) {
#pragma unroll
        for (int i = 0; i < 4; ++i) {
          const int r = row0 + wm + mr * 16 + g * 4 + i;
          const int s = r & 2047;
          dstp[(size_t)s * 64 + dcol] = (bf16_t)((acc[mr][nr][i] + bv) * sc);
        }
      }
    }
  }
}

// ---------------------------------------------------------------------------
// fattn v8 (unchanged): QBLK=64 swapped-operand + SPLIT-K for long q-tiles.
// blockIdx.x in [0,48):
//   x in [ 0,16): qt = 31-x,  K-tiles [0,16)    -> partial chunk 0 (no mask)
//   x in [16,32): qt = 47-x,  K-tiles [16,qt+1) -> partial chunk 1 (diag)
//   x in [32,48): qt = 47-x,  K-tiles [0,qt+1)  -> final (qt < 16)
// ---------------------------------------------------------------------------
__global__ __launch_bounds__(256) void fattn(const bf16_t* __restrict__ qw,
                                             const bf16_t* __restrict__ kw,
                                             const bf16_t* __restrict__ vt,
                                             bf16_t* __restrict__ attn,
                                             float* __restrict__ opart,
                                             float* __restrict__ ml) {
  __shared__ __align__(16) bf16_t Ks[2][64][64];
  __shared__ __align__(16) bf16_t Vs[2][64][64];  // rows = d, cols = key
  __shared__ __align__(16) bf16_t Ps[4][16][64];  // wave-private P^T source, swizzled
  const int tid = threadIdx.x;
  const int w = tid >> 6;
  const int lane = tid & 63;
  const int g = lane >> 4;
  const int li = lane & 15;
  const int x = blockIdx.x;
  int qt, ktb, kte, chunk;
  bool split;
  if (x < 16) {
    qt = 31 - x; ktb = 0; kte = 16; chunk = 0; split = true;
  } else if (x < 32) {
    qt = 47 - x; ktb = 16; kte = qt + 1; chunk = 1; split = true;
  } else {
    qt = 47 - x; ktb = 0; kte = qt + 1; chunk = 0; split = false;
  }
  const int h = blockIdx.y;
  const int b = blockIdx.z;
  const size_t base = ((size_t)(b * 8 + h)) * (2048 * 64);
  const int q0 = qt * 64;
  const int qrow = q0 + w * 16 + li;  // this lane's q-row
  const bf16x8 aq0 = *(const bf16x8*)(qw + base + (size_t)qrow * 64 + g * 8);
  const bf16x8 aq1 = *(const bf16x8*)(qw + base + (size_t)qrow * 64 + 32 + g * 8);
  const bf16_t* kbase = kw + base;
  const bf16_t* vbase = vt + base;  // [64][2048]
  const int r_st = tid >> 2;  // staging row 0..63
  const int qu = tid & 3;     // staging quarter
  // prologue: stage tile ktb into buffer 0 (swizzled)
  {
    const bf16_t* kp = kbase + (size_t)(ktb * 64 + r_st) * 64 + qu * 16;
    const bf16_t* vp = vbase + (size_t)r_st * 2048 + ktb * 64 + qu * 16;
    *swz_ptr(&Ks[0][0][0], r_st, qu * 32) = *(const bf16x8*)kp;
    *swz_ptr(&Ks[0][0][0], r_st, qu * 32 + 16) = *(const bf16x8*)(kp + 8);
    *swz_ptr(&Vs[0][0][0], r_st, qu * 32) = *(const bf16x8*)vp;
    *swz_ptr(&Vs[0][0][0], r_st, qu * 32 + 16) = *(const bf16x8*)(vp + 8);
  }
  f32x4 accO[4] = {};  // accO[nt][i] = O^T: q=li, d = nt*16 + g*4 + i
  float m_run = -__builtin_inff();
  float l_run = 0.f;
  // P-row LDS addressing (wave-private, swizzled by (li&7))
  char* const psrow = (char*)&Ps[w][li][0];
  const int pswz = (li & 7) << 4;
  for (int kt = ktb; kt < kte; ++kt) {
    __syncthreads();  // buf[cur] fully staged; previous compute done
    const int cur = (kt - ktb) & 1;
    const bool pf = (kt + 1) < kte;
    // T14: issue next tile's global loads now; they land during the MFMA phase
    bf16x8 nk0, nk1, nv0, nv1;
    if (pf) {
      const int kb2 = (kt + 1) * 64;
      const bf16_t* kp = kbase + (size_t)(kb2 + r_st) * 64 + qu * 16;
      const bf16_t* vp = vbase + (size_t)r_st * 2048 + kb2 + qu * 16;
      nk0 = *(const bf16x8*)kp;
      nk1 = *(const bf16x8*)(kp + 8);
      nv0 = *(const bf16x8*)vp;
      nv1 = *(const bf16x8*)(vp + 8);
    }
    // S^T tile: sv[nt][i] = S[q = li][key = kb + nt*16 + g*4 + i]
    f32x4 sv[4];
    __builtin_amdgcn_s_setprio(1);
#pragma unroll
    for (int nt = 0; nt < 4; ++nt) {
      const bf16x8 bk0 = *swz_cptr(&Ks[cur][0][0], nt * 16 + li, g * 16);
      const bf16x8 bk1 = *swz_cptr(&Ks[cur][0][0], nt * 16 + li, 64 + g * 16);
      f32x4 z = {0.f, 0.f, 0.f, 0.f};
      z = MFMA(bk0, aq0, z);
      sv[nt] = MFMA(bk1, aq1, z);
    }
    __builtin_amdgcn_s_setprio(0);
    if (kt == qt) {  // diagonal tile mask: key > q-row
#pragma unroll
      for (int nt = 0; nt < 4; ++nt)
#pragma unroll
        for (int i = 0; i < 4; ++i)
          if (nt * 16 + g * 4 + i > w * 16 + li) sv[nt][i] = NEGV;
    }
    // row max: 15 in-lane + 2 shuffles
    float pmax = sv[0][0];
#pragma unroll
    for (int nt = 0; nt < 4; ++nt)
#pragma unroll
      for (int i = 0; i < 4; ++i) pmax = fmaxf(pmax, sv[nt][i]);
    pmax = fmaxf(pmax, __shfl_xor(pmax, 16, 64));
    pmax = fmaxf(pmax, __shfl_xor(pmax, 32, 64));
    // T13 defer-max: only rescale when max grew by > 8 (log2 domain)
    if (!__all(pmax - m_run <= 8.f)) {
      const float newm = fmaxf(m_run, pmax);
      const float sc = exp2f(m_run - newm);
      l_run *= sc;
      m_run = newm;
#pragma unroll
      for (int nt = 0; nt < 4; ++nt)
#pragma unroll
        for (int i = 0; i < 4; ++i) accO[nt][i] *= sc;
    }
    // P = exp2(S - m), in-lane sum + 2 shuffles
    float rsum = 0.f;
#pragma unroll
    for (int nt = 0; nt < 4; ++nt) {
#pragma unroll
      for (int i = 0; i < 4; ++i) {
        const float p = exp2f(sv[nt][i] - m_run);
        sv[nt][i] = p;
        rsum += p;
      }
    }
    rsum += __shfl_xor(rsum, 16, 64);
    rsum += __shfl_xor(rsum, 32, 64);
    l_run += rsum;
    // P -> wave-private LDS, packed bf16x4, XOR-swizzled (4 x ds_write_b64)
#pragma unroll
    for (int nt = 0; nt < 4; ++nt) {
      bf16x4 pk;
#pragma unroll
      for (int i = 0; i < 4; ++i) pk[i] = (bf16_t)sv[nt][i];
      *(bf16x4*)(psrow + ((nt * 32 + g * 8) ^ pswz)) = pk;
    }
    const bf16x8 ap0 = *(const bf16x8*)(psrow + ((g * 16) ^ pswz));
    const bf16x8 ap1 = *(const bf16x8*)(psrow + ((64 + g * 16) ^ pswz));
    // O^T += V^T * P^T
    __builtin_amdgcn_s_setprio(1);
#pragma unroll
    for (int nt = 0; nt < 4; ++nt) {
      const bf16x8 bv0 = *swz_cptr(&Vs[cur][0][0], nt * 16 + li, g * 16);
      const bf16x8 bv1 = *swz_cptr(&Vs[cur][0][0], nt * 16 + li, 64 + g * 16);
      accO[nt] = MFMA(bv0, ap0, accO[nt]);
      accO[nt] = MFMA(bv1, ap1, accO[nt]);
    }
    __builtin_amdgcn_s_setprio(0);
    // write next tile's staged regs into the other buffer (before next barrier)
    if (pf) {
      *swz_ptr(&Ks[cur ^ 1][0][0], r_st, qu * 32) = nk0;
      *swz_ptr(&Ks[cur ^ 1][0][0], r_st, qu * 32 + 16) = nk1;
      *swz_ptr(&Vs[cur ^ 1][0][0], r_st, qu * 32) = nv0;
      *swz_ptr(&Vs[cur ^ 1][0][0], r_st, qu * 32 + 16) = nv1;
    }
  }
  if (!split) {
    // final: normalized, PRE-SWIZZLED store for out_gemm (row&7 == li&7)
    const float inv = 1.0f / l_run;
    bf16_t* arow = attn + (size_t)(b * 2048 + qrow) * 512 + h * 64;
#pragma unroll
    for (int nt = 0; nt < 4; ++nt) {
      bf16x4 pk;
#pragma unroll
      for (int i = 0; i < 4; ++i) pk[i] = (bf16_t)(accO[nt][i] * inv);
      *(bf16x4*)&arow[8 * ((nt * 2 + (g >> 1)) ^ (li & 7)) + (g & 1) * 4] = pk;
    }
  } else {
    // partial: unnormalized O^T f32 + (m, l) per row
    const int row = w * 16 + li;
    const size_t pbase = (((size_t)(b * 8 + h) * 16 + (qt - 16)) * 2 + chunk) * 64 + row;
    float* op = opart + pbase * 64;
#pragma unroll
    for (int nt = 0; nt < 4; ++nt) *(f32x4*)&op[nt * 16 + g * 4] = accO[nt];
    if (g == 0) {
      ml[pbase * 2] = m_run;
      ml[pbase * 2 + 1] = l_run;
    }
  }
}

// ---------------------------------------------------------------------------
// fcombine: merge the two split-K partials for qt in [16,32) and write the
// normalized, pre-swizzled attn rows. grid (16 qt, 8 h, 4 b), 256 threads.
// ---------------------------------------------------------------------------
__global__ __launch_bounds__(256) void fcombine(const float* __restrict__ opart,
                                                const float* __restrict__ ml,
                                                bf16_t* __restrict__ attn) {
  const int qi = blockIdx.x;  // qt = 16 + qi
  const int h = blockIdx.y;
  const int b = blockIdx.z;
  const int tid = threadIdx.x;
  const int row = tid >> 2;
  const int dq = (tid & 3) * 16;
  const size_t base2 = ((size_t)(b * 8 + h) * 16 + qi) * 2;
  const size_t p0 = (base2 * 64 + row);
  const size_t p1 = ((base2 + 1) * 64 + row);
  const float m1 = ml[p0 * 2], l1 = ml[p0 * 2 + 1];
  const float m2 = ml[p1 * 2], l2 = ml[p1 * 2 + 1];
  const float m = fmaxf(m1, m2);
  const float w1 = exp2f(m1 - m), w2 = exp2f(m2 - m);
  const float inv = 1.0f / (l1 * w1 + l2 * w2);
  const float* o1 = opart + p0 * 64;
  const float* o2 = opart + p1 * 64;
  const int qrow = (16 + qi) * 64 + row;
  bf16_t* arow = attn + (size_t)(b * 2048 + qrow) * 512 + h * 64;
#pragma unroll
  for (int t = 0; t < 2; ++t) {
    const int c0 = dq + t * 8;
    const f32x4 a1 = *(const f32x4*)&o1[c0];
    const f32x4 b1 = *(const f32x4*)&o1[c0 + 4];
    const f32x4 a2 = *(const f32x4*)&o2[c0];
    const f32x4 b2 = *(const f32x4*)&o2[c0 + 4];
    bf16x8 v;
#pragma unroll
    for (int i = 0; i < 4; ++i) {
      v[i] = (bf16_t)((a1[i] * w1 + a2[i] * w2) * inv);
      v[4 + i] = (bf16_t)((b1[i] * w1 + b2[i] * w2) * inv);
    }
    *(bf16x8*)&arow[8 * ((c0 >> 3) ^ (row & 7))] = v;
  }
}

// ---------------------------------------------------------------------------
// out_gemm v9: counted-vmcnt double-buffered gload_lds pipeline (T4), 1 nf
// per block. A = attn (pre-swizzled), B = BmatT (transposed, pre-swizzled).
// grid (64 m-tiles, 4 col-tiles, 8 forecast)
// ---------------------------------------------------------------------------
__global__ __launch_bounds__(256) void out_gemm(const bf16_t* __restrict__ A,
                                                const bf16_t* __restrict__ BmatT,
                                                const float* __restrict__ bo,
                                                float* __restrict__ out) {
  __shared__ __align__(16) bf16_t As[2][128 * 64];
  __shared__ __align__(16) bf16_t Bs[2][128 * 64];
  const int tid = threadIdx.x;
  const int wave = tid >> 6, lane = tid & 63;
  const int g = lane >> 4, li = lane & 15;
  const int row0 = blockIdx.x * 128;
  const int col0 = blockIdx.y * 128;
  const int nf = blockIdx.z;
  const int wm = (wave >> 1) * 64, wn = (wave & 1) * 64;
  f32x4 acc[4][4] = {};
  const bf16_t* asrc = A + (size_t)(row0 + wave * 32 + (lane >> 3)) * 512 + (lane & 7) * 8;
  const bf16_t* bsrc = BmatT + (size_t)nf * 512 * 512 +
                       (size_t)(col0 + wave * 32 + (lane >> 3)) * 512 + (lane & 7) * 8;
  bf16_t* adst0 = &As[0][wave * 32 * 64];
  bf16_t* adst1 = &As[1][wave * 32 * 64];
  bf16_t* bdst0 = &Bs[0][wave * 32 * 64];
  bf16_t* bdst1 = &Bs[1][wave * 32 * 64];
  auto stage = [&](int bi, int kt) {
    const int k0 = kt * 64;
    bf16_t* ad = bi ? adst1 : adst0;
    bf16_t* bd = bi ? bdst1 : bdst0;
#pragma unroll
    for (int c = 0; c < 4; ++c) {
      gload16(asrc + (size_t)c * 8 * 512 + k0, ad + c * 512);
      gload16(bsrc + (size_t)c * 8 * 512 + k0, bd + c * 512);
    }
  };
  stage(0, 0);
#pragma unroll
  for (int t = 0; t < 8; ++t) {
    const int cur = t & 1;
    if (t < 7) {
      stage(cur ^ 1, t + 1);
      asm volatile("s_waitcnt vmcnt(8)" ::: "memory");
    } else {
      asm volatile("s_waitcnt vmcnt(0)" ::: "memory");
    }
    __builtin_amdgcn_s_barrier();
    __builtin_amdgcn_sched_barrier(0);
#pragma unroll
    for (int ks = 0; ks < 2; ++ks) {
      bf16x8 af[4], bfr[4];
#pragma unroll
      for (int mr = 0; mr < 4; ++mr)
        af[mr] = *swz_cptr(As[cur], wm + mr * 16 + li, ks * 64 + g * 16);
#pragma unroll
      for (int nr = 0; nr < 4; ++nr)
        bfr[nr] = *swz_cptr(Bs[cur], wn + nr * 16 + li, ks * 64 + g * 16);
#pragma unroll
      for (int mr = 0; mr < 4; ++mr)
#pragma unroll
        for (int nr = 0; nr < 4; ++nr)
          acc[mr][nr] = MFMA(af[mr], bfr[nr], acc[mr][nr]);
    }
    __builtin_amdgcn_s_barrier();
    __builtin_amdgcn_sched_barrier(0);
  }
  const int bb = row0 >> 11;
  float* obase = out + ((size_t)(bb * 8 + nf)) * (2048 * 512);
#pragma unroll
  for (int nr = 0; nr < 4; ++nr) {
    const int c = col0 + wn + nr * 16 + li;
    const float bv = bo[c];
#pragma unroll
    for (int mr = 0; mr < 4; ++mr) {
#pragma unroll
      for (int i = 0; i < 4; ++i) {
        const int r = row0 + wm + mr * 16 + g * 4 + i;
        const int s = r & 2047;
        obase[(size_t)s * 512 + c] = acc[mr][nr][i] + bv;
      }
    }
  }
}

// ---------------------------------------------------------------------------
extern "C" void kernel_launch(void* const* d_in, const int* in_sizes, int n_in,
                              void* d_out, int out_size, void* d_ws, size_t ws_size,
                              hipStream_t stream) {
  const float* query = (const float*)d_in[0];
  // d_in[1]=key, d_in[2]=value are unused by the reference forward.
  const float* Wqkv = (const float*)d_in[3];
  const float* bqkv = (const float*)d_in[4];
  const float* Wo = (const float*)d_in[5];
  const float* bo = (const float*)d_in[6];
  const float* Xi = (const float*)d_in[7];
  float* out = (float*)d_out;

  char* ws = (char*)d_ws;
  bf16_t* qw = (bf16_t*)(ws + 0);                 // [4][8][2048][64] bf16 = 8 MiB (pre-scaled)
  bf16_t* kw = (bf16_t*)(ws + 8388608);           // 8 MiB
  bf16_t* vt = (bf16_t*)(ws + 16777216);          // [4][8][64][2048] bf16 = 8 MiB (transposed)
  // Xb and attn SHARE this region: Xb consumed by qkv_gemm, then fattn
  // overwrites it with attn (sequential stream order makes this safe).
  bf16_t* Xb = (bf16_t*)(ws + 25165824);          // [8192][512] bf16 = 8 MiB (pre-swizzled)
  bf16_t* attn = (bf16_t*)(ws + 25165824);        // [8192][512] bf16 = 8 MiB (pre-swizzled)
  bf16_t* BmatT = (bf16_t*)(ws + 33554432);       // [8][512][512] bf16 = 4 MiB (T, pre-swizzled)
  float* pows = (float*)(ws + 37748736);          // [8][8][64][64] f32 = 1 MiB
  bf16_t* WT = (bf16_t*)(ws + 38797312);          // [1536][512] bf16 = 1.5 MiB (T, pre-swizzled)
  float* opart = (float*)(ws + 40370176);         // [32][16][2][64][64] f32 = 16 MiB
  float* mlbuf = (float*)(ws + 57147392);         // [32][16][2][64][2] f32 = 512 KiB

  xconv<<<dim3(2048), dim3(256), 0, stream>>>(query, Xb);
  wconv<<<dim3(24, 8), dim3(256), 0, stream>>>(Wqkv, WT);
  build_powers<<<dim3(8), dim3(256), 0, stream>>>(Xi, pows);
  build_B<<<dim3(4, 8, 8), dim3(256), 0, stream>>>(pows, Wo, BmatT);
  qkv_gemm<<<dim3(64, 12), dim3(256), 0, stream>>>(Xb, WT, bqkv, qw, kw, vt);
  fattn<<<dim3(48, 8, 4), dim3(256), 0, stream>>>(qw, kw, vt, attn, opart, mlbuf);
  fcombine<<<dim3(16, 8, 4), dim3(256), 0, stream>>>(opart, mlbuf, attn);
  out_gemm<<<dim3(64, 4, 8), dim3(256), 0, stream>>>(attn, BmatT, bo, out);
}

// Round 10
// 179.119 us; speedup vs baseline: 1.1553x; 1.0257x over previous
//
#include <hip/hip_runtime.h>
#include <math.h>

// Problem constants: N=4, L=2048, E=512, H=8, hd=64, FORECAST=8
// M = N*L = 8192 token rows.

#define NEGV -1e30f

typedef __bf16 bf16_t;
typedef __bf16 bf16x4 __attribute__((ext_vector_type(4)));
typedef __bf16 bf16x8 __attribute__((ext_vector_type(8)));
typedef float f32x4 __attribute__((ext_vector_type(4)));
typedef unsigned u32x4 __attribute__((ext_vector_type(4)));

#define MFMA(a, b, c) __builtin_amdgcn_mfma_f32_16x16x32_bf16((a), (b), (c), 0, 0, 0)

// 0.125 * log2(e): folded into Q so scores are already in log2 domain.
#define QSCALE 0.18033688011112042f

// Swizzled LDS access for [*][64]-bf16 tiles (row stride 128 B):
// byte = r*128 + (colbyte ^ ((r&7)<<4)).  Applied on BOTH write and read
// (fattn K/V), or on read-only when the source was PRE-swizzled (GEMMs).
__device__ __forceinline__ bf16x8* swz_ptr(bf16_t* base, int r, int cb) {
  return (bf16x8*)((char*)base + r * 128 + (cb ^ ((r & 7) << 4)));
}
__device__ __forceinline__ const bf16x8* swz_cptr(const bf16_t* base, int r, int cb) {
  return (const bf16x8*)((const char*)base + r * 128 + (cb ^ ((r & 7) << 4)));
}

// async global->LDS, 16 B per lane. LDS dest is wave-uniform base + lane*16;
// global src is per-lane.
__device__ __forceinline__ void gload16(const bf16_t* g, bf16_t* l) {
  __builtin_amdgcn_global_load_lds(
      (const __attribute__((address_space(1))) void*)g,
      (__attribute__((address_space(3))) void*)l, 16, 0, 0);
}

// pack two f32 -> u32 of 2 bf16 (no builtin on gfx950; single VALU op)
__device__ __forceinline__ unsigned cvt_pk_bf16(float lo, float hi) {
  unsigned r;
  asm("v_cvt_pk_bf16_f32 %0, %1, %2" : "=v"(r) : "v"(lo), "v"(hi));
  return r;
}

// Pre-swizzle: logical col c (0..63) of a row r stored at:
//   c' = (c & 7) | 8*(((c>>3) ^ (r & 7)) & 7)   [within each 64-col k-block]

// ---------------------------------------------------------------------------
// prep: fused {build_powers | wconv | xconv} (independent preprocessing).
//   bx in [0,8):    build_powers head h=bx
//   bx in [8,200):  wconv tile (n0,k0)
//   bx in [200,2248): xconv chunk
// ---------------------------------------------------------------------------
__global__ __launch_bounds__(256) void prep(const float* __restrict__ X,
                                            const float* __restrict__ W,
                                            const float* __restrict__ Xi,
                                            bf16_t* __restrict__ Xb,
                                            bf16_t* __restrict__ WT,
                                            float* __restrict__ pows) {
  __shared__ __align__(16) char smem[2 * 64 * 68 * 4];
  const int bx = blockIdx.x;
  const int tid = threadIdx.x;
  if (bx < 8) {
    // ---- build_powers: P = I + (Xi - Xi^T); pows[h][n] = P^(n+1), f32 ----
    const int h = bx;
    float (*P)[68] = (float(*)[68])smem;
    float (*cur)[68] = (float(*)[68])(smem + 64 * 68 * 4);
    const float* xi = Xi + (size_t)h * 4096;
    float* dst = pows + (size_t)h * 8 * 4096;
    for (int idx = tid; idx < 4096; idx += 256) {
      const int i = idx >> 6, j = idx & 63;
      const float p = (i == j ? 1.f : 0.f) + xi[i * 64 + j] - xi[j * 64 + i];
      P[i][j] = p;
      cur[i][j] = p;
      dst[idx] = p;  // n=0 -> P^1
    }
    __syncthreads();
    const int i = tid >> 2;
    const int j0 = (tid & 3) * 16;
    for (int n = 1; n < 8; ++n) {
      float a[16];
#pragma unroll
      for (int jj = 0; jj < 16; ++jj) a[jj] = 0.f;
      for (int dd = 0; dd < 64; ++dd) {
        const float c = cur[i][dd];
#pragma unroll
        for (int jj = 0; jj < 16; ++jj) a[jj] += c * P[dd][j0 + jj];
      }
      __syncthreads();
#pragma unroll
      for (int jj = 0; jj < 16; ++jj) {
        cur[i][j0 + jj] = a[jj];
        dst[n * 4096 + i * 64 + j0 + jj] = a[jj];
      }
      __syncthreads();
    }
  } else if (bx < 200) {
    // ---- wconv: WT[n][k] = bf16(Wqkv[k][n]), transposed + pre-swizzled ----
    const int idx = bx - 8;
    const int n0 = (idx % 24) * 64, k0 = (idx / 24) * 64;
    float (*Wf)[65] = (float(*)[65])smem;
#pragma unroll
    for (int c = 0; c < 16; ++c) {
      const int id2 = tid + c * 256;
      const int kk = id2 >> 6, nn = id2 & 63;
      Wf[kk][nn] = W[(size_t)(k0 + kk) * 1536 + n0 + nn];
    }
    __syncthreads();
    const int nr = tid >> 2;
    const int jb = (tid & 3) * 2;
#pragma unroll
    for (int t = 0; t < 2; ++t) {
      const int j = jb + t;
      bf16x8 v;
#pragma unroll
      for (int i = 0; i < 8; ++i) v[i] = (bf16_t)Wf[j * 8 + i][nr];
      *(bf16x8*)&WT[(size_t)(n0 + nr) * 512 + k0 + 8 * (j ^ (nr & 7))] = v;
    }
  } else {
    // ---- xconv: Xb[s][k] = bf16(X[s][k]), pre-swizzled ----
    const int gid = (bx - 200) * 256 + tid;
    const int s = gid >> 6, j = gid & 63;
    const float4* src = (const float4*)(X + (size_t)s * 512 + j * 8);
    const float4 f0 = src[0], f1 = src[1];
    bf16x8 v;
    v[0] = (bf16_t)f0.x; v[1] = (bf16_t)f0.y; v[2] = (bf16_t)f0.z; v[3] = (bf16_t)f0.w;
    v[4] = (bf16_t)f1.x; v[5] = (bf16_t)f1.y; v[6] = (bf16_t)f1.z; v[7] = (bf16_t)f1.w;
    *(bf16x8*)&Xb[(size_t)s * 512 + (j >> 3) * 64 + 8 * ((j & 7) ^ (s & 7))] = v;
  }
}

// ---------------------------------------------------------------------------
// build_B: BmatT[n][e][(h*64+d)] = sum_dd pows[h][n][d][dd] * Wo[h*64+dd][e]
// Output TRANSPOSED [e][k] and PRE-SWIZZLED within each head's 64-col block.
// grid (4 e-tiles, 8 n, 8 h).
// ---------------------------------------------------------------------------
__global__ __launch_bounds__(256) void build_B(const float* __restrict__ pows,
                                               const float* __restrict__ Wo,
                                               bf16_t* __restrict__ BmatT) {
  const int et = blockIdx.x;
  const int n = blockIdx.y;
  const int h = blockIdx.z;
  __shared__ __align__(16) float P[64][68];
  __shared__ __align__(16) float We[64][128];
  const int tid = threadIdx.x;
  const float* src = pows + ((size_t)h * 8 + n) * 4096;
  for (int idx = tid; idx < 4096; idx += 256) P[idx >> 6][idx & 63] = src[idx];
  const int e0 = et * 128;
  for (int idx = tid; idx < 8192; idx += 256) {
    const int dd = idx >> 7, e = idx & 127;
    We[dd][e] = Wo[(size_t)(h * 64 + dd) * 512 + e0 + e];
  }
  __syncthreads();
  const int d = tid >> 2;
  const int eq = (tid & 3) * 32;  // multiple of 32 -> (e&7) == (j&7)
  float acc[32];
#pragma unroll
  for (int j = 0; j < 32; ++j) acc[j] = 0.f;
  for (int dd = 0; dd < 64; ++dd) {
    const float p = P[d][dd];
#pragma unroll
    for (int j = 0; j < 32; ++j) acc[j] += p * We[dd][eq + j];
  }
  bf16_t* dst = BmatT + (size_t)n * 512 * 512 + (size_t)(e0 + eq) * 512 + h * 64;
  const int dlo = d & 7, dhi = d >> 3;
#pragma unroll
  for (int j = 0; j < 32; ++j)
    dst[(size_t)j * 512 + 8 * (dhi ^ (j & 7)) + dlo] = (bf16_t)acc[j];
}

// ---------------------------------------------------------------------------
// qkv_gemm: counted-vmcnt double-buffered gload_lds pipeline.
// A=Xb (pre-swizzled bf16), B=WT (transposed, pre-swizzled bf16).
// ---------------------------------------------------------------------------
__global__ __launch_bounds__(256) void qkv_gemm(const bf16_t* __restrict__ Xb,
                                                const bf16_t* __restrict__ WT,
                                                const float* __restrict__ bias,
                                                bf16_t* __restrict__ qw,
                                                bf16_t* __restrict__ kw,
                                                bf16_t* __restrict__ vt) {
  __shared__ __align__(16) bf16_t As[2][128 * 64];
  __shared__ __align__(16) bf16_t Bs[2][128 * 64];
  const int tid = threadIdx.x;
  const int wave = tid >> 6, lane = tid & 63;
  const int g = lane >> 4, li = lane & 15;
  const int row0 = blockIdx.x * 128;
  const int col0 = blockIdx.y * 128;
  const int wm = (wave >> 1) * 64, wn = (wave & 1) * 64;
  f32x4 acc[4][4] = {};
  const bf16_t* asrc = Xb + (size_t)(row0 + wave * 32 + (lane >> 3)) * 512 + (lane & 7) * 8;
  const bf16_t* bsrc = WT + (size_t)(col0 + wave * 32 + (lane >> 3)) * 512 + (lane & 7) * 8;
  bf16_t* adst0 = &As[0][wave * 32 * 64];
  bf16_t* adst1 = &As[1][wave * 32 * 64];
  bf16_t* bdst0 = &Bs[0][wave * 32 * 64];
  bf16_t* bdst1 = &Bs[1][wave * 32 * 64];
  auto stage = [&](int bi, int kt) {
    const int k0 = kt * 64;
    bf16_t* ad = bi ? adst1 : adst0;
    bf16_t* bd = bi ? bdst1 : bdst0;
#pragma unroll
    for (int c = 0; c < 4; ++c) {
      gload16(asrc + (size_t)c * 8 * 512 + k0, ad + c * 512);
      gload16(bsrc + (size_t)c * 8 * 512 + k0, bd + c * 512);
    }
  };
  stage(0, 0);
#pragma unroll
  for (int t = 0; t < 8; ++t) {
    const int cur = t & 1;
    if (t < 7) {
      stage(cur ^ 1, t + 1);
      asm volatile("s_waitcnt vmcnt(8)" ::: "memory");
    } else {
      asm volatile("s_waitcnt vmcnt(0)" ::: "memory");
    }
    __builtin_amdgcn_s_barrier();
    __builtin_amdgcn_sched_barrier(0);
#pragma unroll
    for (int ks = 0; ks < 2; ++ks) {
      bf16x8 af[4], bfr[4];
#pragma unroll
      for (int mr = 0; mr < 4; ++mr)
        af[mr] = *swz_cptr(As[cur], wm + mr * 16 + li, ks * 64 + g * 16);
#pragma unroll
      for (int nr = 0; nr < 4; ++nr)
        bfr[nr] = *swz_cptr(Bs[cur], wn + nr * 16 + li, ks * 64 + g * 16);
#pragma unroll
      for (int mr = 0; mr < 4; ++mr)
#pragma unroll
        for (int nr = 0; nr < 4; ++nr)
          acc[mr][nr] = MFMA(af[mr], bfr[nr], acc[mr][nr]);
    }
    __builtin_amdgcn_s_barrier();
    __builtin_amdgcn_sched_barrier(0);
  }
  // epilogue
  const int cbase = col0 + wn;            // multiple of 64
  const int sel = cbase >> 9;             // 0=q 1=k 2=v (uniform per wave)
  const int hh = (cbase & 511) >> 6;      // head (uniform per wave)
  const int bb = row0 >> 11;              // batch (uniform per block)
  const size_t hb = (size_t)(bb * 8 + hh) * (2048 * 64);
  if (sel == 2) {
    // v: transposed store vt[d][s], packed bf16x4 along s
    bf16_t* vbase = vt + hb;
#pragma unroll
    for (int nr = 0; nr < 4; ++nr) {
      const int dcol = nr * 16 + li;
      const float bv = bias[cbase + dcol];
#pragma unroll
      for (int mr = 0; mr < 4; ++mr) {
        bf16x4 pk;
#pragma unroll
        for (int i = 0; i < 4; ++i) pk[i] = (bf16_t)(acc[mr][nr][i] + bv);
        const int s = (row0 + wm + mr * 16 + g * 4) & 2047;
        *(bf16x4*)&vbase[(size_t)dcol * 2048 + s] = pk;
      }
    }
  } else {
    bf16_t* dstp = (sel == 0 ? qw : kw) + hb;
    const float sc = (sel == 0) ? QSCALE : 1.0f;
#pragma unroll
    for (int nr = 0; nr < 4; ++nr) {
      const int dcol = nr * 16 + li;
      const float bv = bias[cbase + dcol];
#pragma unroll
      for (int mr = 0; mr < 4; ++mr) {
#pragma unroll
        for (int i = 0; i < 4; ++i) {
          const int r = row0 + wm + mr * 16 + g * 4 + i;
          const int s = r & 2047;
          dstp[(size_t)s * 64 + dcol] = (bf16_t)((acc[mr][nr][i] + bv) * sc);
        }
      }
    }
  }
}

// ---------------------------------------------------------------------------
// fattn v10: QBLK=64 swapped-operand + split-K (r8 structure) + T12
// in-register P redistribution: cvt_pk_bf16 packs, then
// permlane32_swap + permlane16_swap move P into the PV B-operand layout.
// No P LDS round-trip; Ps array deleted (LDS 40960 -> 32768 B).
// Mapping (derived & element-checked): lane (g,li) holds P[li][16nt+4g+i];
// PV needs ap0[j]=P[li][8g+j], ap1[j]=P[li][32+8g+j].
//   (u,v) = swap32(pk[nt],pk[nt+1]); (p,q) = swap16(u,v)
//   apX = {p(h=0), p(h=1), q(h=0), q(h=1)}
// ---------------------------------------------------------------------------
__global__ __launch_bounds__(256) void fattn(const bf16_t* __restrict__ qw,
                                             const bf16_t* __restrict__ kw,
                                             const bf16_t* __restrict__ vt,
                                             bf16_t* __restrict__ attn,
                                             float* __restrict__ opart,
                                             float* __restrict__ ml) {
  __shared__ __align__(16) bf16_t Ks[2][64][64];
  __shared__ __align__(16) bf16_t Vs[2][64][64];  // rows = d, cols = key
  const int tid = threadIdx.x;
  const int w = tid >> 6;
  const int lane = tid & 63;
  const int g = lane >> 4;
  const int li = lane & 15;
  const int x = blockIdx.x;
  int qt, ktb, kte, chunk;
  bool split;
  if (x < 16) {
    qt = 31 - x; ktb = 0; kte = 16; chunk = 0; split = true;
  } else if (x < 32) {
    qt = 47 - x; ktb = 16; kte = qt + 1; chunk = 1; split = true;
  } else {
    qt = 47 - x; ktb = 0; kte = qt + 1; chunk = 0; split = false;
  }
  const int h = blockIdx.y;
  const int b = blockIdx.z;
  const size_t base = ((size_t)(b * 8 + h)) * (2048 * 64);
  const int q0 = qt * 64;
  const int qrow = q0 + w * 16 + li;  // this lane's q-row
  const bf16x8 aq0 = *(const bf16x8*)(qw + base + (size_t)qrow * 64 + g * 8);
  const bf16x8 aq1 = *(const bf16x8*)(qw + base + (size_t)qrow * 64 + 32 + g * 8);
  const bf16_t* kbase = kw + base;
  const bf16_t* vbase = vt + base;  // [64][2048]
  const int r_st = tid >> 2;  // staging row 0..63
  const int qu = tid & 3;     // staging quarter
  // prologue: stage tile ktb into buffer 0 (swizzled)
  {
    const bf16_t* kp = kbase + (size_t)(ktb * 64 + r_st) * 64 + qu * 16;
    const bf16_t* vp = vbase + (size_t)r_st * 2048 + ktb * 64 + qu * 16;
    *swz_ptr(&Ks[0][0][0], r_st, qu * 32) = *(const bf16x8*)kp;
    *swz_ptr(&Ks[0][0][0], r_st, qu * 32 + 16) = *(const bf16x8*)(kp + 8);
    *swz_ptr(&Vs[0][0][0], r_st, qu * 32) = *(const bf16x8*)vp;
    *swz_ptr(&Vs[0][0][0], r_st, qu * 32 + 16) = *(const bf16x8*)(vp + 8);
  }
  f32x4 accO[4] = {};  // accO[nt][i] = O^T: q=li, d = nt*16 + g*4 + i
  float m_run = -__builtin_inff();
  float l_run = 0.f;
  for (int kt = ktb; kt < kte; ++kt) {
    __syncthreads();  // buf[cur] fully staged; previous compute done
    const int cur = (kt - ktb) & 1;
    const bool pf = (kt + 1) < kte;
    // T14: issue next tile's global loads now; they land during the MFMA phase
    bf16x8 nk0, nk1, nv0, nv1;
    if (pf) {
      const int kb2 = (kt + 1) * 64;
      const bf16_t* kp = kbase + (size_t)(kb2 + r_st) * 64 + qu * 16;
      const bf16_t* vp = vbase + (size_t)r_st * 2048 + kb2 + qu * 16;
      nk0 = *(const bf16x8*)kp;
      nk1 = *(const bf16x8*)(kp + 8);
      nv0 = *(const bf16x8*)vp;
      nv1 = *(const bf16x8*)(vp + 8);
    }
    // S^T tile: sv[nt][i] = S[q = li][key = kb + nt*16 + g*4 + i]
    f32x4 sv[4];
    __builtin_amdgcn_s_setprio(1);
#pragma unroll
    for (int nt = 0; nt < 4; ++nt) {
      const bf16x8 bk0 = *swz_cptr(&Ks[cur][0][0], nt * 16 + li, g * 16);
      const bf16x8 bk1 = *swz_cptr(&Ks[cur][0][0], nt * 16 + li, 64 + g * 16);
      f32x4 z = {0.f, 0.f, 0.f, 0.f};
      z = MFMA(bk0, aq0, z);
      sv[nt] = MFMA(bk1, aq1, z);
    }
    __builtin_amdgcn_s_setprio(0);
    if (kt == qt) {  // diagonal tile mask: key > q-row
#pragma unroll
      for (int nt = 0; nt < 4; ++nt)
#pragma unroll
        for (int i = 0; i < 4; ++i)
          if (nt * 16 + g * 4 + i > w * 16 + li) sv[nt][i] = NEGV;
    }
    // row max: 15 in-lane + 2 shuffles
    float pmax = sv[0][0];
#pragma unroll
    for (int nt = 0; nt < 4; ++nt)
#pragma unroll
      for (int i = 0; i < 4; ++i) pmax = fmaxf(pmax, sv[nt][i]);
    pmax = fmaxf(pmax, __shfl_xor(pmax, 16, 64));
    pmax = fmaxf(pmax, __shfl_xor(pmax, 32, 64));
    // T13 defer-max: only rescale when max grew by > 8 (log2 domain)
    if (!__all(pmax - m_run <= 8.f)) {
      const float newm = fmaxf(m_run, pmax);
      const float sc = exp2f(m_run - newm);
      l_run *= sc;
      m_run = newm;
#pragma unroll
      for (int nt = 0; nt < 4; ++nt)
#pragma unroll
        for (int i = 0; i < 4; ++i) accO[nt][i] *= sc;
    }
    // P = exp2(S - m), in-lane sum + 2 shuffles
    float rsum = 0.f;
#pragma unroll
    for (int nt = 0; nt < 4; ++nt) {
#pragma unroll
      for (int i = 0; i < 4; ++i) {
        const float p = exp2f(sv[nt][i] - m_run);
        sv[nt][i] = p;
        rsum += p;
      }
    }
    rsum += __shfl_xor(rsum, 16, 64);
    rsum += __shfl_xor(rsum, 32, 64);
    l_run += rsum;
    // T12: P -> bf16 in-register; redistribute via permlane swaps (no LDS).
    const unsigned pk00 = cvt_pk_bf16(sv[0][0], sv[0][1]);
    const unsigned pk01 = cvt_pk_bf16(sv[0][2], sv[0][3]);
    const unsigned pk10 = cvt_pk_bf16(sv[1][0], sv[1][1]);
    const unsigned pk11 = cvt_pk_bf16(sv[1][2], sv[1][3]);
    const unsigned pk20 = cvt_pk_bf16(sv[2][0], sv[2][1]);
    const unsigned pk21 = cvt_pk_bf16(sv[2][2], sv[2][3]);
    const unsigned pk30 = cvt_pk_bf16(sv[3][0], sv[3][1]);
    const unsigned pk31 = cvt_pk_bf16(sv[3][2], sv[3][3]);
    bf16x8 ap0, ap1;
    {
      auto s0 = __builtin_amdgcn_permlane32_swap((int)pk00, (int)pk10, false, false);
      auto t0 = __builtin_amdgcn_permlane16_swap(s0[0], s0[1], false, false);
      auto s1 = __builtin_amdgcn_permlane32_swap((int)pk01, (int)pk11, false, false);
      auto t1 = __builtin_amdgcn_permlane16_swap(s1[0], s1[1], false, false);
      u32x4 wd = {(unsigned)t0[0], (unsigned)t1[0], (unsigned)t0[1], (unsigned)t1[1]};
      ap0 = __builtin_bit_cast(bf16x8, wd);
    }
    {
      auto s0 = __builtin_amdgcn_permlane32_swap((int)pk20, (int)pk30, false, false);
      auto t0 = __builtin_amdgcn_permlane16_swap(s0[0], s0[1], false, false);
      auto s1 = __builtin_amdgcn_permlane32_swap((int)pk21, (int)pk31, false, false);
      auto t1 = __builtin_amdgcn_permlane16_swap(s1[0], s1[1], false, false);
      u32x4 wd = {(unsigned)t0[0], (unsigned)t1[0], (unsigned)t0[1], (unsigned)t1[1]};
      ap1 = __builtin_bit_cast(bf16x8, wd);
    }
    // O^T += V^T * P^T
    __builtin_amdgcn_s_setprio(1);
#pragma unroll
    for (int nt = 0; nt < 4; ++nt) {
      const bf16x8 bv0 = *swz_cptr(&Vs[cur][0][0], nt * 16 + li, g * 16);
      const bf16x8 bv1 = *swz_cptr(&Vs[cur][0][0], nt * 16 + li, 64 + g * 16);
      accO[nt] = MFMA(bv0, ap0, accO[nt]);
      accO[nt] = MFMA(bv1, ap1, accO[nt]);
    }
    __builtin_amdgcn_s_setprio(0);
    // write next tile's staged regs into the other buffer (before next barrier)
    if (pf) {
      *swz_ptr(&Ks[cur ^ 1][0][0], r_st, qu * 32) = nk0;
      *swz_ptr(&Ks[cur ^ 1][0][0], r_st, qu * 32 + 16) = nk1;
      *swz_ptr(&Vs[cur ^ 1][0][0], r_st, qu * 32) = nv0;
      *swz_ptr(&Vs[cur ^ 1][0][0], r_st, qu * 32 + 16) = nv1;
    }
  }
  if (!split) {
    // final: normalized, PRE-SWIZZLED store for out_gemm (row&7 == li&7)
    const float inv = 1.0f / l_run;
    bf16_t* arow = attn + (size_t)(b * 2048 + qrow) * 512 + h * 64;
#pragma unroll
    for (int nt = 0; nt < 4; ++nt) {
      bf16x4 pk;
#pragma unroll
      for (int i = 0; i < 4; ++i) pk[i] = (bf16_t)(accO[nt][i] * inv);
      *(bf16x4*)&arow[8 * ((nt * 2 + (g >> 1)) ^ (li & 7)) + (g & 1) * 4] = pk;
    }
  } else {
    // partial: unnormalized O^T f32 + (m, l) per row
    const int row = w * 16 + li;
    const size_t pbase = (((size_t)(b * 8 + h) * 16 + (qt - 16)) * 2 + chunk) * 64 + row;
    float* op = opart + pbase * 64;
#pragma unroll
    for (int nt = 0; nt < 4; ++nt) *(f32x4*)&op[nt * 16 + g * 4] = accO[nt];
    if (g == 0) {
      ml[pbase * 2] = m_run;
      ml[pbase * 2 + 1] = l_run;
    }
  }
}

// ---------------------------------------------------------------------------
// fcombine: merge the two split-K partials for qt in [16,32) and write the
// normalized, pre-swizzled attn rows. grid (16 qt, 8 h, 4 b), 256 threads.
// ---------------------------------------------------------------------------
__global__ __launch_bounds__(256) void fcombine(const float* __restrict__ opart,
                                                const float* __restrict__ ml,
                                                bf16_t* __restrict__ attn) {
  const int qi = blockIdx.x;  // qt = 16 + qi
  const int h = blockIdx.y;
  const int b = blockIdx.z;
  const int tid = threadIdx.x;
  const int row = tid >> 2;
  const int dq = (tid & 3) * 16;
  const size_t base2 = ((size_t)(b * 8 + h) * 16 + qi) * 2;
  const size_t p0 = (base2 * 64 + row);
  const size_t p1 = ((base2 + 1) * 64 + row);
  const float m1 = ml[p0 * 2], l1 = ml[p0 * 2 + 1];
  const float m2 = ml[p1 * 2], l2 = ml[p1 * 2 + 1];
  const float m = fmaxf(m1, m2);
  const float w1 = exp2f(m1 - m), w2 = exp2f(m2 - m);
  const float inv = 1.0f / (l1 * w1 + l2 * w2);
  const float* o1 = opart + p0 * 64;
  const float* o2 = opart + p1 * 64;
  const int qrow = (16 + qi) * 64 + row;
  bf16_t* arow = attn + (size_t)(b * 2048 + qrow) * 512 + h * 64;
#pragma unroll
  for (int t = 0; t < 2; ++t) {
    const int c0 = dq + t * 8;
    const f32x4 a1 = *(const f32x4*)&o1[c0];
    const f32x4 b1 = *(const f32x4*)&o1[c0 + 4];
    const f32x4 a2 = *(const f32x4*)&o2[c0];
    const f32x4 b2 = *(const f32x4*)&o2[c0 + 4];
    bf16x8 v;
#pragma unroll
    for (int i = 0; i < 4; ++i) {
      v[i] = (bf16_t)((a1[i] * w1 + a2[i] * w2) * inv);
      v[4 + i] = (bf16_t)((b1[i] * w1 + b2[i] * w2) * inv);
    }
    *(bf16x8*)&arow[8 * ((c0 >> 3) ^ (row & 7))] = v;
  }
}

// ---------------------------------------------------------------------------
// out_gemm: counted-vmcnt double-buffered gload_lds pipeline, 1 nf per block.
// A = attn (pre-swizzled), B = BmatT (transposed, pre-swizzled).
// grid (64 m-tiles, 4 col-tiles, 8 forecast)
// ---------------------------------------------------------------------------
__global__ __launch_bounds__(256) void out_gemm(const bf16_t* __restrict__ A,
                                                const bf16_t* __restrict__ BmatT,
                                                const float* __restrict__ bo,
                                                float* __restrict__ out) {
  __shared__ __align__(16) bf16_t As[2][128 * 64];
  __shared__ __align__(16) bf16_t Bs[2][128 * 64];
  const int tid = threadIdx.x;
  const int wave = tid >> 6, lane = tid & 63;
  const int g = lane >> 4, li = lane & 15;
  const int row0 = blockIdx.x * 128;
  const int col0 = blockIdx.y * 128;
  const int nf = blockIdx.z;
  const int wm = (wave >> 1) * 64, wn = (wave & 1) * 64;
  f32x4 acc[4][4] = {};
  const bf16_t* asrc = A + (size_t)(row0 + wave * 32 + (lane >> 3)) * 512 + (lane & 7) * 8;
  const bf16_t* bsrc = BmatT + (size_t)nf * 512 * 512 +
                       (size_t)(col0 + wave * 32 + (lane >> 3)) * 512 + (lane & 7) * 8;
  bf16_t* adst0 = &As[0][wave * 32 * 64];
  bf16_t* adst1 = &As[1][wave * 32 * 64];
  bf16_t* bdst0 = &Bs[0][wave * 32 * 64];
  bf16_t* bdst1 = &Bs[1][wave * 32 * 64];
  auto stage = [&](int bi, int kt) {
    const int k0 = kt * 64;
    bf16_t* ad = bi ? adst1 : adst0;
    bf16_t* bd = bi ? bdst1 : bdst0;
#pragma unroll
    for (int c = 0; c < 4; ++c) {
      gload16(asrc + (size_t)c * 8 * 512 + k0, ad + c * 512);
      gload16(bsrc + (size_t)c * 8 * 512 + k0, bd + c * 512);
    }
  };
  stage(0, 0);
#pragma unroll
  for (int t = 0; t < 8; ++t) {
    const int cur = t & 1;
    if (t < 7) {
      stage(cur ^ 1, t + 1);
      asm volatile("s_waitcnt vmcnt(8)" ::: "memory");
    } else {
      asm volatile("s_waitcnt vmcnt(0)" ::: "memory");
    }
    __builtin_amdgcn_s_barrier();
    __builtin_amdgcn_sched_barrier(0);
#pragma unroll
    for (int ks = 0; ks < 2; ++ks) {
      bf16x8 af[4], bfr[4];
#pragma unroll
      for (int mr = 0; mr < 4; ++mr)
        af[mr] = *swz_cptr(As[cur], wm + mr * 16 + li, ks * 64 + g * 16);
#pragma unroll
      for (int nr = 0; nr < 4; ++nr)
        bfr[nr] = *swz_cptr(Bs[cur], wn + nr * 16 + li, ks * 64 + g * 16);
#pragma unroll
      for (int mr = 0; mr < 4; ++mr)
#pragma unroll
        for (int nr = 0; nr < 4; ++nr)
          acc[mr][nr] = MFMA(af[mr], bfr[nr], acc[mr][nr]);
    }
    __builtin_amdgcn_s_barrier();
    __builtin_amdgcn_sched_barrier(0);
  }
  const int bb = row0 >> 11;
  float* obase = out + ((size_t)(bb * 8 + nf)) * (2048 * 512);
#pragma unroll
  for (int nr = 0; nr < 4; ++nr) {
    const int c = col0 + wn + nr * 16 + li;
    const float bv = bo[c];
#pragma unroll
    for (int mr = 0; mr < 4; ++mr) {
#pragma unroll
      for (int i = 0; i < 4; ++i) {
        const int r = row0 + wm + mr * 16 + g * 4 + i;
        const int s = r & 2047;
        obase[(size_t)s * 512 + c] = acc[mr][nr][i] + bv;
      }
    }
  }
}

// ---------------------------------------------------------------------------
extern "C" void kernel_launch(void* const* d_in, const int* in_sizes, int n_in,
                              void* d_out, int out_size, void* d_ws, size_t ws_size,
                              hipStream_t stream) {
  const float* query = (const float*)d_in[0];
  // d_in[1]=key, d_in[2]=value are unused by the reference forward.
  const float* Wqkv = (const float*)d_in[3];
  const float* bqkv = (const float*)d_in[4];
  const float* Wo = (const float*)d_in[5];
  const float* bo = (const float*)d_in[6];
  const float* Xi = (const float*)d_in[7];
  float* out = (float*)d_out;

  char* ws = (char*)d_ws;
  bf16_t* qw = (bf16_t*)(ws + 0);                 // [4][8][2048][64] bf16 = 8 MiB (pre-scaled)
  bf16_t* kw = (bf16_t*)(ws + 8388608);           // 8 MiB
  bf16_t* vt = (bf16_t*)(ws + 16777216);          // [4][8][64][2048] bf16 = 8 MiB (transposed)
  // Xb and attn SHARE this region: Xb consumed by qkv_gemm, then fattn
  // overwrites it with attn (sequential stream order makes this safe).
  bf16_t* Xb = (bf16_t*)(ws + 25165824);          // [8192][512] bf16 = 8 MiB (pre-swizzled)
  bf16_t* attn = (bf16_t*)(ws + 25165824);        // [8192][512] bf16 = 8 MiB (pre-swizzled)
  bf16_t* BmatT = (bf16_t*)(ws + 33554432);       // [8][512][512] bf16 = 4 MiB (T, pre-swizzled)
  float* pows = (float*)(ws + 37748736);          // [8][8][64][64] f32 = 1 MiB
  bf16_t* WT = (bf16_t*)(ws + 38797312);          // [1536][512] bf16 = 1.5 MiB (T, pre-swizzled)
  float* opart = (float*)(ws + 40370176);         // [32][16][2][64][64] f32 = 16 MiB
  float* mlbuf = (float*)(ws + 57147392);         // [32][16][2][64][2] f32 = 512 KiB

  prep<<<dim3(2248), dim3(256), 0, stream>>>(query, Wqkv, Xi, Xb, WT, pows);
  build_B<<<dim3(4, 8, 8), dim3(256), 0, stream>>>(pows, Wo, BmatT);
  qkv_gemm<<<dim3(64, 12), dim3(256), 0, stream>>>(Xb, WT, bqkv, qw, kw, vt);
  fattn<<<dim3(48, 8, 4), dim3(256), 0, stream>>>(qw, kw, vt, attn, opart, mlbuf);
  fcombine<<<dim3(16, 8, 4), dim3(256), 0, stream>>>(opart, mlbuf, attn);
  out_gemm<<<dim3(64, 4, 8), dim3(256), 0, stream>>>(attn, BmatT, bo, out);
}